// Round 14
// baseline (2131.375 us; speedup 1.0000x reference)
//
#include <hip/hip_runtime.h>

#define Bsz 512
#define Lsz 30
#define Hsz 1024
#define Tsz 30

typedef _Float16 f16;
typedef f16 f16x8 __attribute__((ext_vector_type(8)));
typedef unsigned short u16x8 __attribute__((ext_vector_type(8)));
typedef float  f32x4  __attribute__((ext_vector_type(4)));
typedef unsigned int u32;
typedef unsigned short u16;

#define WSCALE 32.0f
#define INVWS  0.03125f
#define INV2   0.0009765625f   // 1/1024

__device__ __forceinline__ u16 h2u(f16 h) {
  union { f16 h; u16 u; } v; v.h = h; return v.u;
}
__device__ __forceinline__ f16x8 ld8h(const u16* p) {
  return *reinterpret_cast<const f16x8*>(p);
}
__device__ __forceinline__ void stage16(const u16* g, u16* l) {
  __builtin_amdgcn_global_load_lds(
      (const __attribute__((address_space(1))) u32*)g,
      (__attribute__((address_space(3))) u32*)l, 16, 0, 0);
}

// ------- split fp32 -> (hi, lo) fp16 planes, pre-scaled by WSCALE --------------
__global__ __launch_bounds__(256) void k_split(
    const float* __restrict__ src, u16* __restrict__ hi,
    u16* __restrict__ lo, int n4)
{
  const int i = blockIdx.x * 256 + threadIdx.x;
  if (i >= n4) return;
  const float4 v = ((const float4*)src)[i];
  const float f[4] = { v.x * WSCALE, v.y * WSCALE, v.z * WSCALE, v.w * WSCALE };
  u16 h[4], l[4];
  #pragma unroll
  for (int j = 0; j < 4; ++j) {
    const f16 hb = (f16)f[j];
    const f16 lb = (f16)(f[j] - (float)hb);
    h[j] = h2u(hb); l[j] = h2u(lb);
  }
  ((ushort4*)hi)[i] = make_ushort4(h[0], h[1], h[2], h[3]);
  ((ushort4*)lo)[i] = make_ushort4(l[0], l[1], l[2], l[3]);
}

// -------- transpose + scaled fp16 2-plane split: out[k][n] = in[n][k] (Wl) -----
__global__ __launch_bounds__(256) void k_splitT2(
    const float* __restrict__ src, u16* __restrict__ t0, u16* __restrict__ t1)
{
  __shared__ float t[32][33];
  const int tid = threadIdx.x;
  const int bi = blockIdx.x * 32, bj = blockIdx.y * 32;
  const int r = tid >> 3, c4 = (tid & 7) * 4;
  const float4 v = *(const float4*)(src + (size_t)(bi + r) * Hsz + bj + c4);
  t[r][c4] = v.x; t[r][c4 + 1] = v.y; t[r][c4 + 2] = v.z; t[r][c4 + 3] = v.w;
  __syncthreads();
  u16 h[4], l[4];
  #pragma unroll
  for (int i = 0; i < 4; ++i) {
    const float f = t[c4 + i][r] * WSCALE;
    const f16 hb = (f16)f;
    const f16 lb = (f16)(f - (float)hb);
    h[i] = h2u(hb); l[i] = h2u(lb);
  }
  const size_t o = (size_t)(bj + r) * Hsz + bi + c4;
  *(ushort4*)(t0 + o) = make_ushort4(h[0], h[1], h[2], h[3]);
  *(ushort4*)(t1 + o) = make_ushort4(l[0], l[1], l[2], l[3]);
}

// -------- x0 planes: replicate split(S*32) to 512 rows -------------------------
__global__ __launch_bounds__(256) void k_x0(
    const float* __restrict__ S, u16* __restrict__ xh, u16* __restrict__ xl)
{
  const int b = blockIdx.x, tid = threadIdx.x;
  const float4 v = ((const float4*)S)[tid];
  const float f[4] = { v.x * WSCALE, v.y * WSCALE, v.z * WSCALE, v.w * WSCALE };
  u16 h[4], l[4];
  #pragma unroll
  for (int j = 0; j < 4; ++j) {
    const f16 hb = (f16)f[j];
    const f16 lb = (f16)(f[j] - (float)hb);
    h[j] = h2u(hb); l[j] = h2u(lb);
  }
  const size_t o = (size_t)b * Hsz + tid * 4;
  *(ushort4*)(xh + o) = make_ushort4(h[0], h[1], h[2], h[3]);
  *(ushort4*)(xl + o) = make_ushort4(l[0], l[1], l[2], l[3]);
}

// ------ init: h0 = mean_L(ih), scaled h fp16 splits, c0 = Wl_b . ih, valid -----
__global__ __launch_bounds__(256) void k_init(
    const float* __restrict__ ih, const int* __restrict__ pos,
    const float* __restrict__ wlb,
    float* __restrict__ hf, u16* __restrict__ hh,
    u16* __restrict__ hl, float* __restrict__ c0,
    u32* __restrict__ valid)
{
  __shared__ float red[4];
  const int b = blockIdx.x, tid = threadIdx.x;
  const int lane = tid & 63, wid = tid >> 6;
  const float4 wb = ((const float4*)wlb)[tid];
  float s0 = 0.f, s1 = 0.f, s2 = 0.f, s3 = 0.f;
  for (int l = 0; l < Lsz; ++l) {
    const float4 v = ((const float4*)(ih + ((size_t)b * Lsz + l) * Hsz))[tid];
    s0 += v.x; s1 += v.y; s2 += v.z; s3 += v.w;
    float part = v.x * wb.x + v.y * wb.y + v.z * wb.z + v.w * wb.w;
    #pragma unroll
    for (int off = 32; off >= 1; off >>= 1) part += __shfl_xor(part, off, 64);
    if (lane == 0) red[wid] = part;
    __syncthreads();
    if (tid == 0) c0[b * Lsz + l] = red[0] + red[1] + red[2] + red[3];
    __syncthreads();
  }
  const size_t o = (size_t)b * Hsz + tid * 4;
  const float m[4] = { s0 / 30.f, s1 / 30.f, s2 / 30.f, s3 / 30.f };
  *(float4*)(hf + o) = make_float4(m[0], m[1], m[2], m[3]);
  u16 h4[4], l4[4];
  #pragma unroll
  for (int j = 0; j < 4; ++j) {
    const float hs = m[j] * WSCALE;
    const f16 hb = (f16)hs;
    const f16 lb = (f16)(hs - (float)hb);
    h4[j] = h2u(hb); l4[j] = h2u(lb);
  }
  *(ushort4*)(hh + o) = make_ushort4(h4[0], h4[1], h4[2], h4[3]);
  *(ushort4*)(hl + o) = make_ushort4(l4[0], l4[1], l4[2], l4[3]);
  if (tid == 0) {
    int ss = 0;
    for (int l = 0; l < Lsz; ++l) ss += (pos[b * Lsz + l] != -1) ? 1 : 0;
    valid[b] = (ss >= 32) ? 0xFFFFFFFFu : ((1u << ss) - 1u);
  }
}

// ============ G GEMM: 3-pass fp16, A reg-split from fp32, dbuf, XCD swizzle ====
__global__ __launch_bounds__(256) void k_gemmG(
    const float* __restrict__ Afp,
    const u16* __restrict__ Bh, const u16* __restrict__ Bl,
    u16* __restrict__ Ch, u16* __restrict__ Cl)
{
  constexpr int oAh = 0, oAl = 4096, oBh = 8192, oBl = 12288;
  __shared__ u16 lds[2][16384];

  const int tid = threadIdx.x;
  const int w = tid >> 6, lane = tid & 63;
  const int wm = w >> 1, wn = w & 1;
  const int lr = lane & 15, lg = lane >> 4;

  const int nwg = gridDim.x * gridDim.y;
  int lin = blockIdx.y * gridDim.x + blockIdx.x;
  lin = (lin & 7) * (nwg >> 3) + (lin >> 3);
  const int bm = (lin / gridDim.x) * 128, bn = (lin % gridDim.x) * 128;

  const int ar = tid & 127, kh = tid >> 7;
  const float* aptr = Afp + (size_t)(bm + ar) * Hsz + kh * 16;
  const int awo0 = (ar >> 4) * 512 + ((ar & 15) + 32 * kh) * 8;

  const u16* gpB[4]; int bwo[4];
  #pragma unroll
  for (int i = 0; i < 4; ++i) {
    const int cid = (w << 2) | i;
    const u16* base; int g, off;
    if (cid < 8) { base = Bh; g = cid;     off = oBh + g * 512; }
    else         { base = Bl; g = cid - 8; off = oBl + g * 512; }
    gpB[i] = base + (size_t)(bn + g * 16 + lr) * Hsz + lg * 8;
    bwo[i] = off;
  }

  float4 areg[4];
  #define LOAD_A() { _Pragma("unroll") for (int i = 0; i < 4; ++i) areg[i] = ((const float4*)aptr)[i]; aptr += 32; }
  #define STAGE_B(buf) { _Pragma("unroll") for (int i = 0; i < 4; ++i) { stage16(gpB[i], &lds[buf][bwo[i]]); gpB[i] += 32; } }
  #define WRITE_A(buf) { \
    u16x8 h0v, h1v, l0v, l1v; \
    _Pragma("unroll") for (int i = 0; i < 4; ++i) { \
      const float f[4] = { areg[i].x, areg[i].y, areg[i].z, areg[i].w }; \
      _Pragma("unroll") for (int c = 0; c < 4; ++c) { \
        const int j = 4 * i + c; \
        const f16 hb = (f16)f[c]; \
        const f16 lb = (f16)(f[c] - (float)hb); \
        if (j < 8) { h0v[j] = h2u(hb); l0v[j] = h2u(lb); } \
        else       { h1v[j - 8] = h2u(hb); l1v[j - 8] = h2u(lb); } \
      } \
    } \
    *(u16x8*)&lds[buf][oAh + awo0]       = h0v; \
    *(u16x8*)&lds[buf][oAh + awo0 + 128] = h1v; \
    *(u16x8*)&lds[buf][oAl + awo0]       = l0v; \
    *(u16x8*)&lds[buf][oAl + awo0 + 128] = l1v; }

  f32x4 acc[4][4] = {};

  LOAD_A();
  STAGE_B(0);
  WRITE_A(0);
  __syncthreads();

  for (int ks = 0; ks < 32; ++ks) {
    const int cur = ks & 1;
    if (ks < 31) { STAGE_B(cur ^ 1); LOAD_A(); }
    {
      const u16* L = &lds[cur][0];
      f16x8 a_h[4], a_l[4], b_h[4], b_l[4];
      #pragma unroll
      for (int m = 0; m < 4; ++m) {
        const int g = wm * 4 + m;
        a_h[m] = ld8h(L + oAh + g * 512 + lane * 8);
        a_l[m] = ld8h(L + oAl + g * 512 + lane * 8);
      }
      #pragma unroll
      for (int n = 0; n < 4; ++n) {
        const int g = wn * 4 + n;
        b_h[n] = ld8h(L + oBh + g * 512 + lane * 8);
        b_l[n] = ld8h(L + oBl + g * 512 + lane * 8);
      }
      #pragma unroll
      for (int m = 0; m < 4; ++m)
        #pragma unroll
        for (int n = 0; n < 4; ++n) {
          acc[m][n] = __builtin_amdgcn_mfma_f32_16x16x32_f16(a_h[m], b_h[n], acc[m][n], 0, 0, 0);
          acc[m][n] = __builtin_amdgcn_mfma_f32_16x16x32_f16(a_h[m], b_l[n], acc[m][n], 0, 0, 0);
          acc[m][n] = __builtin_amdgcn_mfma_f32_16x16x32_f16(a_l[m], b_h[n], acc[m][n], 0, 0, 0);
        }
    }
    __syncthreads();
    if (ks < 31) { WRITE_A(cur ^ 1); __syncthreads(); }
  }

  #pragma unroll
  for (int n = 0; n < 4; ++n) {
    const int col = bn + wn * 64 + n * 16 + lr;
    #pragma unroll
    for (int m = 0; m < 4; ++m) {
      #pragma unroll
      for (int rr = 0; rr < 4; ++rr) {
        const int row = bm + wm * 64 + m * 16 + lg * 4 + rr;
        const float v = acc[m][n][rr];                // = 32 * G
        const f16 hb = (f16)v;
        const f16 lb = (f16)(v - (float)hb);
        Ch[(size_t)row * Hsz + col] = h2u(hb);
        Cl[(size_t)row * Hsz + col] = h2u(lb);
      }
    }
  }
  #undef LOAD_A
  #undef STAGE_B
  #undef WRITE_A
}

// ============ ghc2: (gh + gi) GEMMs + GRU combine, fully self-contained ========
// 512 thr (8 waves), out 64 rows x 32 cols x 3 gates, grid 256 (8bm x 32bn).
// LDS: W planes only (WHh 6, WHl 6, WIh 6, WIl 6 chunks x 512 u16), dbuf 48KB.
// H and X fragments are direct per-lane register loads (2-wave redundancy).
__global__ __launch_bounds__(512) void k_ghc2(
    const u16* __restrict__ Hh, const u16* __restrict__ Hl,
    const u16* __restrict__ Xh, const u16* __restrict__ Xl, int rmul, int radd,
    const u16* __restrict__ WHh, const u16* __restrict__ WHl,
    const u16* __restrict__ WIh, const u16* __restrict__ WIl,
    const float* __restrict__ bih, const float* __restrict__ bhh,
    const float* __restrict__ hf_in, float* __restrict__ hf_out,
    u16* __restrict__ hho, u16* __restrict__ hlo,
    u16* __restrict__ Hph, u16* __restrict__ Hpl, int tstep)
{
  constexpr int oWHh = 0, oWHl = 3072, oWIh = 6144, oWIl = 9216;
  __shared__ u16 lds[2][12288];

  const int bn = (blockIdx.x & 31) * 32, bm = (blockIdx.x >> 5) * 64;
  const int tid = threadIdx.x;
  const int w = tid >> 6, lane = tid & 63;
  const int wm = w >> 1, wn = w & 1;
  const int lr = lane & 15, lg = lane >> 4;

  // W stager: 24 chunks over 8 waves (3 each)
  const u16* gp[3]; int ldso[3];
  #pragma unroll
  for (int i = 0; i < 3; ++i) {
    const int cid = w + 8 * i;
    const u16* base; int g, off;
    if (cid < 6)       { g = cid;      base = WHh; off = oWHh + g * 512; }
    else if (cid < 12) { g = cid - 6;  base = WHl; off = oWHl + g * 512; }
    else if (cid < 18) { g = cid - 12; base = WIh; off = oWIh + g * 512; }
    else               { g = cid - 18; base = WIl; off = oWIl + g * 512; }
    const long row = (g >> 1) * 1024 + bn + (g & 1) * 16 + lr;
    gp[i] = base + row * Hsz + lg * 8;
    ldso[i] = off;
  }

  // A-frag pointers (per-lane direct loads)
  const int rowA = bm + wm * 16 + lr;
  const u16* hhp = Hh + (size_t)rowA * Hsz + lg * 8;
  const u16* hlp = Hl + (size_t)rowA * Hsz + lg * 8;
  const long xrow = (long)rowA * rmul + radd;
  const u16* xhp = Xh + xrow * Hsz + lg * 8;
  const u16* xlp = Xl + xrow * Hsz + lg * 8;

  // acc: 0=r (H+X), 1=z (H+X), 2=i_n (X), 3=h_n (H)
  f32x4 acc[4] = {};

  f16x8 cHh = ld8h(hhp), cHl = ld8h(hlp), cXh = ld8h(xhp), cXl = ld8h(xlp);
  #pragma unroll
  for (int i = 0; i < 3; ++i) { stage16(gp[i], &lds[0][ldso[i]]); gp[i] += 32; }
  __syncthreads();

  for (int ks = 0; ks < 32; ++ks) {
    const int cur = ks & 1;
    f16x8 nHh, nHl, nXh, nXl;
    if (ks < 31) {
      #pragma unroll
      for (int i = 0; i < 3; ++i) { stage16(gp[i], &lds[cur ^ 1][ldso[i]]); gp[i] += 32; }
      const int ko = (ks + 1) * 32;
      nHh = ld8h(hhp + ko); nHl = ld8h(hlp + ko);
      nXh = ld8h(xhp + ko); nXl = ld8h(xlp + ko);
    }
    const u16* L = &lds[cur][0];
    #pragma unroll
    for (int gt = 0; gt < 3; ++gt) {
      const int g = gt * 2 + wn;
      const f16x8 bhh_ = ld8h(L + oWHh + g * 512 + lane * 8);
      const f16x8 bhl_ = ld8h(L + oWHl + g * 512 + lane * 8);
      const f16x8 bih_ = ld8h(L + oWIh + g * 512 + lane * 8);
      const f16x8 bil_ = ld8h(L + oWIl + g * 512 + lane * 8);
      const int ai = (gt == 2) ? 3 : gt;
      const int xi = (gt == 2) ? 2 : gt;
      acc[ai] = __builtin_amdgcn_mfma_f32_16x16x32_f16(cHh, bhh_, acc[ai], 0, 0, 0);
      acc[ai] = __builtin_amdgcn_mfma_f32_16x16x32_f16(cHh, bhl_, acc[ai], 0, 0, 0);
      acc[ai] = __builtin_amdgcn_mfma_f32_16x16x32_f16(cHl, bhh_, acc[ai], 0, 0, 0);
      acc[xi] = __builtin_amdgcn_mfma_f32_16x16x32_f16(cXh, bih_, acc[xi], 0, 0, 0);
      acc[xi] = __builtin_amdgcn_mfma_f32_16x16x32_f16(cXh, bil_, acc[xi], 0, 0, 0);
      acc[xi] = __builtin_amdgcn_mfma_f32_16x16x32_f16(cXl, bih_, acc[xi], 0, 0, 0);
    }
    __syncthreads();
    if (ks < 31) { cHh = nHh; cHl = nHl; cXh = nXh; cXl = nXl; }
  }

  const int c = bn + wn * 16 + lr;
  const float b_ir = bih[c], b_iz = bih[1024 + c], b_in = bih[2048 + c];
  const float b_hr = bhh[c], b_hz = bhh[1024 + c], b_hn = bhh[2048 + c];
  #pragma unroll
  for (int rr = 0; rr < 4; ++rr) {
    const int row = bm + wm * 16 + lg * 4 + rr;
    const float pr = acc[0][rr] * INV2 + b_ir + b_hr;
    const float pz = acc[1][rr] * INV2 + b_iz + b_hz;
    const float r = 1.f / (1.f + expf(-pr));
    const float z = 1.f / (1.f + expf(-pz));
    const float n = tanhf(acc[2][rr] * INV2 + b_in + r * (acc[3][rr] * INV2 + b_hn));
    const size_t o = (size_t)row * Hsz + c;
    const float h = (1.f - z) * n + z * hf_in[o];
    hf_out[o] = h;
    const float hs = h * WSCALE;
    const f16 hb = (f16)hs;
    const f16 lb = (f16)(hs - (float)hb);
    hho[o] = h2u(hb);
    hlo[o] = h2u(lb);
    const size_t o2 = ((size_t)row * Tsz + tstep) * Hsz + c;
    Hph[o2] = h2u(hb);
    Hpl[o2] = h2u(lb);
  }
}

// ============ PRE: P[b][t][l] = h[t] . G[b][l]  (3-pass fp16, per-batch) =======
__global__ __launch_bounds__(256) void k_pre(
    const u16* __restrict__ Hph, const u16* __restrict__ Hpl,
    const u16* __restrict__ Gh, const u16* __restrict__ Gl,
    float* __restrict__ P)
{
  const int b = blockIdx.x;
  const int w = threadIdx.x >> 6, lane = threadIdx.x & 63;
  const int wm = w >> 1, wn = w & 1;
  const int lr = lane & 15, lg = lane >> 4;

  const int t_ = wm * 16 + lr;
  const int l_ = wn * 16 + lr;
  const size_t abase = ((size_t)b * Tsz + t_) * Hsz + lg * 8;
  const size_t bbase = ((size_t)b * Tsz + l_) * Hsz + lg * 8;

  f32x4 acc = {};
  for (int k0 = 0; k0 < Hsz; k0 += 32) {
    const f16x8 ah = ld8h(Hph + abase + k0);
    const f16x8 al = ld8h(Hpl + abase + k0);
    const f16x8 bh = ld8h(Gh + bbase + k0);
    const f16x8 bl = ld8h(Gl + bbase + k0);
    acc = __builtin_amdgcn_mfma_f32_16x16x32_f16(ah, bh, acc, 0, 0, 0);
    acc = __builtin_amdgcn_mfma_f32_16x16x32_f16(ah, bl, acc, 0, 0, 0);
    acc = __builtin_amdgcn_mfma_f32_16x16x32_f16(al, bh, acc, 0, 0, 0);
  }

  #pragma unroll
  for (int rr = 0; rr < 4; ++rr) {
    const int tr = wm * 16 + lg * 4 + rr;
    P[(size_t)b * 1024 + tr * 32 + wn * 16 + lr] = acc[rr] * INV2;
  }
}

// ============ SM: masked softmax + argmax/flag chain, outputs ==================
__global__ __launch_bounds__(64) void k_sm(
    const float* __restrict__ P, const float* __restrict__ c0,
    const u32* __restrict__ valid, float* __restrict__ out)
{
  const int b = blockIdx.x;
  const int l = threadIdx.x;
  const bool act = (l < Lsz);
  const float c0l = act ? c0[b * Lsz + l] : 0.f;
  const u32 vmask = valid[b];
  u32 fl = 0;

  for (int t = 0; t < Tsz; ++t) {
    const float pre = act ? (P[(size_t)b * 1024 + t * 32 + l] + c0l) : 0.f;
    if (act) out[(size_t)b * (Tsz * Lsz) + t * Lsz + l] = pre;
    const u32 ex = fl | ~vmask;
    const bool ok = act && !((ex >> l) & 1u);
    const float v = ok ? pre : -3.4e38f;
    float best = v;
    #pragma unroll
    for (int off = 32; off >= 1; off >>= 1) best = fmaxf(best, __shfl_xor(best, off, 64));
    const unsigned long long msk = __ballot(v == best);
    const int am = __ffsll((long long)msk) - 1;
    const float e = ok ? expf(pre - best) : 0.f;
    float sum = e;
    #pragma unroll
    for (int off = 32; off >= 1; off >>= 1) sum += __shfl_xor(sum, off, 64);
    if (act)
      out[(size_t)Bsz * Tsz * Lsz + (size_t)b * (Tsz * Lsz) + t * Lsz + l] = e / sum;
    fl |= (1u << am);
  }
}

extern "C" void kernel_launch(void* const* d_in, const int* in_sizes, int n_in,
                              void* d_out, int out_size, void* d_ws, size_t ws_size,
                              hipStream_t stream) {
  const float* ih  = (const float*)d_in[0];
  const float* tg  = (const float*)d_in[1];
  const int*   pos = (const int*)d_in[2];
  const float* S   = (const float*)d_in[4];
  const float* wih = (const float*)d_in[5];
  const float* whh = (const float*)d_in[6];
  const float* bih = (const float*)d_in[7];
  const float* bhh = (const float*)d_in[8];
  const float* wlw = (const float*)d_in[9];
  const float* wlb = (const float*)d_in[10];
  float* out = (float*)d_out;

  const size_t NW3 = (size_t)3 * Hsz * Hsz;
  const size_t NW1 = (size_t)Hsz * Hsz;
  const size_t NH  = (size_t)Bsz * Hsz;
  const size_t NX  = (size_t)Bsz * Tsz * Hsz;        // 15.7M
  const size_t NPL = ((size_t)Bsz * Tsz + 2) * Hsz;  // padded plane rows

  char* p = (char*)d_ws;
  u16* wihh = (u16*)p; p += NW3 * 2;
  u16* wihl = (u16*)p; p += NW3 * 2;
  u16* whhh = (u16*)p; p += NW3 * 2;
  u16* whhl = (u16*)p; p += NW3 * 2;
  u16* wlt0 = (u16*)p; p += NW1 * 2;
  u16* wlt1 = (u16*)p; p += NW1 * 2;
  u16* xth  = (u16*)p; p += NX * 2;                  // tgt planes 31.5 MB each
  u16* xtl  = (u16*)p; p += NX * 2;
  u16* x0h  = (u16*)p; p += NH * 2;                  // S replicated planes
  u16* x0l  = (u16*)p; p += NH * 2;
  u16* Gh   = (u16*)p; p += NPL * 2;
  u16* Gl   = (u16*)p; p += NPL * 2;
  u16* Hph  = (u16*)p; p += NPL * 2;
  u16* Hpl  = (u16*)p; p += NPL * 2;
  float* P   = (float*)p; p += (size_t)Bsz * 1024 * 4;
  float* c0  = (float*)p; p += (size_t)Bsz * Lsz * 4;
  float* hfb[2]; u16* hhb[2]; u16* hlb[2];
  hfb[0] = (float*)p; p += NH * 4;
  hfb[1] = (float*)p; p += NH * 4;
  hhb[0] = (u16*)p; p += NH * 2;
  hlb[0] = (u16*)p; p += NH * 2;
  hhb[1] = (u16*)p; p += NH * 2;
  hlb[1] = (u16*)p; p += NH * 2;
  u32* valid = (u32*)p; p += Bsz * 4;

  k_split<<<(int)(NW3 / 4 + 255) / 256, 256, 0, stream>>>(wih, wihh, wihl, (int)(NW3 / 4));
  k_split<<<(int)(NW3 / 4 + 255) / 256, 256, 0, stream>>>(whh, whhh, whhl, (int)(NW3 / 4));
  k_split<<<(int)(NX / 4 + 255) / 256, 256, 0, stream>>>(tg, xth, xtl, (int)(NX / 4));
  k_splitT2<<<dim3(32, 32), 256, 0, stream>>>(wlw, wlt0, wlt1);
  k_x0<<<Bsz, 256, 0, stream>>>(S, x0h, x0l);
  k_init<<<Bsz, 256, 0, stream>>>(ih, pos, wlb, hfb[0], hhb[0], hlb[0], c0, valid);
  // G planes = (ih @ WlT) * 32, fp16 hi/lo
  k_gemmG<<<dim3(8, 120), 256, 0, stream>>>(ih, wlt0, wlt1, Gh, Gl);

  for (int t = 0; t < Tsz; ++t) {
    const int ci = t & 1, ni = (t + 1) & 1;
    const u16* xh = (t == 0) ? x0h : xth;
    const u16* xl = (t == 0) ? x0l : xtl;
    const int rmul = (t == 0) ? 1 : Tsz;
    const int radd = (t == 0) ? 0 : (t - 1);
    k_ghc2<<<256, 512, 0, stream>>>(hhb[ci], hlb[ci], xh, xl, rmul, radd,
                                    whhh, whhl, wihh, wihl, bih, bhh,
                                    hfb[ci], hfb[ni], hhb[ni], hlb[ni],
                                    Hph, Hpl, t);
  }

  k_pre<<<Bsz, 256, 0, stream>>>(Hph, Hpl, Gh, Gl, P);
  k_sm<<<Bsz, 64, 0, stream>>>(P, c0, valid, out);
}

// Round 16
// 1779.330 us; speedup vs baseline: 1.1979x; 1.1979x over previous
//
#include <hip/hip_runtime.h>

#define Bsz 512
#define Lsz 30
#define Hsz 1024
#define Tsz 30

typedef _Float16 f16;
typedef f16 f16x8 __attribute__((ext_vector_type(8)));
typedef unsigned short u16x8 __attribute__((ext_vector_type(8)));
typedef float  f32x4  __attribute__((ext_vector_type(4)));
typedef unsigned int u32;
typedef unsigned short u16;

#define WSCALE 32.0f
#define INVWS  0.03125f
#define INV2   0.0009765625f   // 1/1024

__device__ __forceinline__ u16 h2u(f16 h) {
  union { f16 h; u16 u; } v; v.h = h; return v.u;
}
__device__ __forceinline__ f16x8 ld8h(const u16* p) {
  return *reinterpret_cast<const f16x8*>(p);
}
__device__ __forceinline__ void stage16(const u16* g, u16* l) {
  __builtin_amdgcn_global_load_lds(
      (const __attribute__((address_space(1))) u32*)g,
      (__attribute__((address_space(3))) u32*)l, 16, 0, 0);
}

// ------- split fp32 -> (hi, lo) fp16 planes, pre-scaled by WSCALE --------------
__global__ __launch_bounds__(256) void k_split(
    const float* __restrict__ src, u16* __restrict__ hi,
    u16* __restrict__ lo, int n4)
{
  const int i = blockIdx.x * 256 + threadIdx.x;
  if (i >= n4) return;
  const float4 v = ((const float4*)src)[i];
  const float f[4] = { v.x * WSCALE, v.y * WSCALE, v.z * WSCALE, v.w * WSCALE };
  u16 h[4], l[4];
  #pragma unroll
  for (int j = 0; j < 4; ++j) {
    const f16 hb = (f16)f[j];
    const f16 lb = (f16)(f[j] - (float)hb);
    h[j] = h2u(hb); l[j] = h2u(lb);
  }
  ((ushort4*)hi)[i] = make_ushort4(h[0], h[1], h[2], h[3]);
  ((ushort4*)lo)[i] = make_ushort4(l[0], l[1], l[2], l[3]);
}

// -------- transpose + scaled fp16 2-plane split: out[k][n] = in[n][k] (Wl) -----
__global__ __launch_bounds__(256) void k_splitT2(
    const float* __restrict__ src, u16* __restrict__ t0, u16* __restrict__ t1)
{
  __shared__ float t[32][33];
  const int tid = threadIdx.x;
  const int bi = blockIdx.x * 32, bj = blockIdx.y * 32;
  const int r = tid >> 3, c4 = (tid & 7) * 4;
  const float4 v = *(const float4*)(src + (size_t)(bi + r) * Hsz + bj + c4);
  t[r][c4] = v.x; t[r][c4 + 1] = v.y; t[r][c4 + 2] = v.z; t[r][c4 + 3] = v.w;
  __syncthreads();
  u16 h[4], l[4];
  #pragma unroll
  for (int i = 0; i < 4; ++i) {
    const float f = t[c4 + i][r] * WSCALE;
    const f16 hb = (f16)f;
    const f16 lb = (f16)(f - (float)hb);
    h[i] = h2u(hb); l[i] = h2u(lb);
  }
  const size_t o = (size_t)(bj + r) * Hsz + bi + c4;
  *(ushort4*)(t0 + o) = make_ushort4(h[0], h[1], h[2], h[3]);
  *(ushort4*)(t1 + o) = make_ushort4(l[0], l[1], l[2], l[3]);
}

// ------ init: h0 = mean_L(ih), scaled h fp16 splits, c0 = Wl_b . ih, valid -----
__global__ __launch_bounds__(256) void k_init(
    const float* __restrict__ ih, const int* __restrict__ pos,
    const float* __restrict__ wlb,
    float* __restrict__ hf, u16* __restrict__ hh,
    u16* __restrict__ hl, float* __restrict__ c0,
    u32* __restrict__ valid)
{
  __shared__ float red[4];
  const int b = blockIdx.x, tid = threadIdx.x;
  const int lane = tid & 63, wid = tid >> 6;
  const float4 wb = ((const float4*)wlb)[tid];
  float s0 = 0.f, s1 = 0.f, s2 = 0.f, s3 = 0.f;
  for (int l = 0; l < Lsz; ++l) {
    const float4 v = ((const float4*)(ih + ((size_t)b * Lsz + l) * Hsz))[tid];
    s0 += v.x; s1 += v.y; s2 += v.z; s3 += v.w;
    float part = v.x * wb.x + v.y * wb.y + v.z * wb.z + v.w * wb.w;
    #pragma unroll
    for (int off = 32; off >= 1; off >>= 1) part += __shfl_xor(part, off, 64);
    if (lane == 0) red[wid] = part;
    __syncthreads();
    if (tid == 0) c0[b * Lsz + l] = red[0] + red[1] + red[2] + red[3];
    __syncthreads();
  }
  const size_t o = (size_t)b * Hsz + tid * 4;
  const float m[4] = { s0 / 30.f, s1 / 30.f, s2 / 30.f, s3 / 30.f };
  *(float4*)(hf + o) = make_float4(m[0], m[1], m[2], m[3]);
  u16 h4[4], l4[4];
  #pragma unroll
  for (int j = 0; j < 4; ++j) {
    const float hs = m[j] * WSCALE;
    const f16 hb = (f16)hs;
    const f16 lb = (f16)(hs - (float)hb);
    h4[j] = h2u(hb); l4[j] = h2u(lb);
  }
  *(ushort4*)(hh + o) = make_ushort4(h4[0], h4[1], h4[2], h4[3]);
  *(ushort4*)(hl + o) = make_ushort4(l4[0], l4[1], l4[2], l4[3]);
  if (tid == 0) {
    int ss = 0;
    for (int l = 0; l < Lsz; ++l) ss += (pos[b * Lsz + l] != -1) ? 1 : 0;
    valid[b] = (ss >= 32) ? 0xFFFFFFFFu : ((1u << ss) - 1u);
  }
}

// ---------------- gi0 = S @ W_ih^T (fp32 GEMV, 3072 outputs) -------------------
__global__ __launch_bounds__(256) void k_gemv0(
    const float* __restrict__ S, const float* __restrict__ wih,
    float* __restrict__ gi0)
{
  const int n = blockIdx.x * 64 + (threadIdx.x >> 2);
  const int part = threadIdx.x & 3;
  const float4* s4 = (const float4*)S + part * 64;
  const float4* w4 = (const float4*)(wih + (size_t)n * Hsz) + part * 64;
  float s = 0.f;
  #pragma unroll 8
  for (int i = 0; i < 64; ++i) {
    const float4 a = s4[i], b = w4[i];
    s = fmaf(a.x, b.x, s); s = fmaf(a.y, b.y, s);
    s = fmaf(a.z, b.z, s); s = fmaf(a.w, b.w, s);
  }
  s += __shfl_xor(s, 1, 64);
  s += __shfl_xor(s, 2, 64);
  if (part == 0) gi0[n] = s;
}

// ============ 3-pass fp16 GEMM, A reg-split from fp32, dbuf LDS, XCD swizzle ===
// MODE1 (GI): A-row remap into tgt, fp32 C into 8-slot ring, acc*INVWS.
// MODE0 (G):  plain A rows; acc (=32*G) split into fp16 planes Ch/Cl.
template<int MODE>
__global__ __launch_bounds__(256) void k_tgemm(
    const float* __restrict__ Afp,
    const u16* __restrict__ Bh, const u16* __restrict__ Bl,
    float* __restrict__ C, u16* __restrict__ Ch, u16* __restrict__ Cl,
    int ldc, int t0)
{
  constexpr int oAh = 0, oAl = 4096, oBh = 8192, oBl = 12288;
  __shared__ u16 lds[2][16384];

  const int tid = threadIdx.x;
  const int w = tid >> 6, lane = tid & 63;
  const int wm = w >> 1, wn = w & 1;
  const int lr = lane & 15, lg = lane >> 4;

  const int nwg = gridDim.x * gridDim.y;
  int lin = blockIdx.y * gridDim.x + blockIdx.x;
  lin = (lin & 7) * (nwg >> 3) + (lin >> 3);
  const int bm = (lin / gridDim.x) * 128, bn = (lin % gridDim.x) * 128;

  const int ar = tid & 127, kh = tid >> 7;
  long arow;
  if (MODE == 1) arow = (long)((bm + ar) & 511) * Tsz + (t0 - 1) + ((bm + ar) >> 9);
  else           arow = bm + ar;
  const float* aptr = Afp + arow * Hsz + kh * 16;
  const int awo0 = (ar >> 4) * 512 + ((ar & 15) + 32 * kh) * 8;

  const u16* gpB[4]; int bwo[4];
  #pragma unroll
  for (int i = 0; i < 4; ++i) {
    const int cid = (w << 2) | i;
    const u16* base; int g, off;
    if (cid < 8) { base = Bh; g = cid;     off = oBh + g * 512; }
    else         { base = Bl; g = cid - 8; off = oBl + g * 512; }
    gpB[i] = base + (size_t)(bn + g * 16 + lr) * Hsz + lg * 8;
    bwo[i] = off;
  }

  float4 areg[4];
  #define LOAD_A() { _Pragma("unroll") for (int i = 0; i < 4; ++i) areg[i] = ((const float4*)aptr)[i]; aptr += 32; }
  #define STAGE_B(buf) { _Pragma("unroll") for (int i = 0; i < 4; ++i) { stage16(gpB[i], &lds[buf][bwo[i]]); gpB[i] += 32; } }
  #define WRITE_A(buf) { \
    u16x8 h0v, h1v, l0v, l1v; \
    _Pragma("unroll") for (int i = 0; i < 4; ++i) { \
      const float f[4] = { areg[i].x, areg[i].y, areg[i].z, areg[i].w }; \
      _Pragma("unroll") for (int c = 0; c < 4; ++c) { \
        const int j = 4 * i + c; \
        const f16 hb = (f16)f[c]; \
        const f16 lb = (f16)(f[c] - (float)hb); \
        if (j < 8) { h0v[j] = h2u(hb); l0v[j] = h2u(lb); } \
        else       { h1v[j - 8] = h2u(hb); l1v[j - 8] = h2u(lb); } \
      } \
    } \
    *(u16x8*)&lds[buf][oAh + awo0]       = h0v; \
    *(u16x8*)&lds[buf][oAh + awo0 + 128] = h1v; \
    *(u16x8*)&lds[buf][oAl + awo0]       = l0v; \
    *(u16x8*)&lds[buf][oAl + awo0 + 128] = l1v; }

  f32x4 acc[4][4] = {};

  LOAD_A();
  STAGE_B(0);
  WRITE_A(0);
  __syncthreads();

  for (int ks = 0; ks < 32; ++ks) {
    const int cur = ks & 1;
    if (ks < 31) { STAGE_B(cur ^ 1); LOAD_A(); }
    {
      const u16* L = &lds[cur][0];
      f16x8 a_h[4], a_l[4], b_h[4], b_l[4];
      #pragma unroll
      for (int m = 0; m < 4; ++m) {
        const int g = wm * 4 + m;
        a_h[m] = ld8h(L + oAh + g * 512 + lane * 8);
        a_l[m] = ld8h(L + oAl + g * 512 + lane * 8);
      }
      #pragma unroll
      for (int n = 0; n < 4; ++n) {
        const int g = wn * 4 + n;
        b_h[n] = ld8h(L + oBh + g * 512 + lane * 8);
        b_l[n] = ld8h(L + oBl + g * 512 + lane * 8);
      }
      #pragma unroll
      for (int m = 0; m < 4; ++m)
        #pragma unroll
        for (int n = 0; n < 4; ++n) {
          acc[m][n] = __builtin_amdgcn_mfma_f32_16x16x32_f16(a_h[m], b_h[n], acc[m][n], 0, 0, 0);
          acc[m][n] = __builtin_amdgcn_mfma_f32_16x16x32_f16(a_h[m], b_l[n], acc[m][n], 0, 0, 0);
          acc[m][n] = __builtin_amdgcn_mfma_f32_16x16x32_f16(a_l[m], b_h[n], acc[m][n], 0, 0, 0);
        }
    }
    __syncthreads();
    if (ks < 31) { WRITE_A(cur ^ 1); __syncthreads(); }
  }

  #pragma unroll
  for (int n = 0; n < 4; ++n) {
    const int col = bn + wn * 64 + n * 16 + lr;
    #pragma unroll
    for (int m = 0; m < 4; ++m) {
      #pragma unroll
      for (int rr = 0; rr < 4; ++rr) {
        const int row = bm + wm * 64 + m * 16 + lg * 4 + rr;
        if (MODE == 1) {
          const int slot = (t0 + (row >> 9)) & 7;
          C[((size_t)slot * Bsz + (row & 511)) * 3072 + col] = acc[m][n][rr] * INVWS;
        } else {
          const float v = acc[m][n][rr];                // = 32 * G
          const f16 hb = (f16)v;
          const f16 lb = (f16)(v - (float)hb);
          Ch[(size_t)row * ldc + col] = h2u(hb);
          Cl[(size_t)row * ldc + col] = h2u(lb);
        }
      }
    }
  }
  #undef LOAD_A
  #undef STAGE_B
  #undef WRITE_A
}

// ============ ghc3: gh-GEMM (3 gates) + GRU combine, 64x16 tiles, grid 512 =====
// 256 thr (4 waves), wave w = row-frag. LDS: A 8 chunks + W 6 chunks, dbuf 28KB.
__global__ __launch_bounds__(256) void k_ghc3(
    const u16* __restrict__ Hh, const u16* __restrict__ Hl,
    const u16* __restrict__ WHh, const u16* __restrict__ WHl,
    const float* __restrict__ gi, int gi_rs,
    const float* __restrict__ bih, const float* __restrict__ bhh,
    const float* __restrict__ hf_in, float* __restrict__ hf_out,
    u16* __restrict__ hho, u16* __restrict__ hlo,
    u16* __restrict__ Hph, u16* __restrict__ Hpl, int tstep)
{
  constexpr int oAh = 0, oAl = 2048, oWh = 4096, oWl = 5632;
  __shared__ u16 lds[2][7168];

  const int bn = (blockIdx.x & 63) * 16, bm = (blockIdx.x >> 6) * 64;
  const int tid = threadIdx.x;
  const int w = tid >> 6, lane = tid & 63;
  const int lr = lane & 15, lg = lane >> 4;

  // 14 chunks over 4 waves: wave w takes cid = w, w+4, w+8, (w<2: w+12)
  const u16* gp[4]; int ldso[4];
  const int nch = (w < 2) ? 4 : 3;
  #pragma unroll
  for (int i = 0; i < 4; ++i) {
    const int cid = w + 4 * i;
    if (cid >= 14) break;
    const u16* base; long row; int off;
    if (cid < 4)       { const int g = cid;      row = bm + g * 16 + lr;   base = Hh;  off = oAh + g * 512; }
    else if (cid < 8)  { const int g = cid - 4;  row = bm + g * 16 + lr;   base = Hl;  off = oAl + g * 512; }
    else if (cid < 11) { const int g = cid - 8;  row = g * 1024 + bn + lr; base = WHh; off = oWh + g * 512; }
    else               { const int g = cid - 11; row = g * 1024 + bn + lr; base = WHl; off = oWl + g * 512; }
    gp[i] = base + row * Hsz + lg * 8;
    ldso[i] = off;
  }

  f32x4 acc[3] = {};

  for (int i = 0; i < nch; ++i) { stage16(gp[i], &lds[0][ldso[i]]); gp[i] += 32; }
  __syncthreads();

  for (int ks = 0; ks < 32; ++ks) {
    const int cur = ks & 1;
    if (ks < 31) {
      for (int i = 0; i < nch; ++i) { stage16(gp[i], &lds[cur ^ 1][ldso[i]]); gp[i] += 32; }
    }
    const u16* L = &lds[cur][0];
    const f16x8 ah = ld8h(L + oAh + w * 512 + lane * 8);
    const f16x8 al = ld8h(L + oAl + w * 512 + lane * 8);
    #pragma unroll
    for (int gt = 0; gt < 3; ++gt) {
      const f16x8 bh = ld8h(L + oWh + gt * 512 + lane * 8);
      const f16x8 bl = ld8h(L + oWl + gt * 512 + lane * 8);
      acc[gt] = __builtin_amdgcn_mfma_f32_16x16x32_f16(ah, bh, acc[gt], 0, 0, 0);
      acc[gt] = __builtin_amdgcn_mfma_f32_16x16x32_f16(ah, bl, acc[gt], 0, 0, 0);
      acc[gt] = __builtin_amdgcn_mfma_f32_16x16x32_f16(al, bh, acc[gt], 0, 0, 0);
    }
    __syncthreads();
  }

  const int c = bn + lr;
  const float b_ir = bih[c], b_iz = bih[1024 + c], b_in = bih[2048 + c];
  const float b_hr = bhh[c], b_hz = bhh[1024 + c], b_hn = bhh[2048 + c];
  #pragma unroll
  for (int rr = 0; rr < 4; ++rr) {
    const int row = bm + w * 16 + lg * 4 + rr;
    const size_t gr = (size_t)row * gi_rs;
    const float pr = gi[gr + c]        + b_ir + acc[0][rr] * INV2 + b_hr;
    const float pz = gi[gr + 1024 + c] + b_iz + acc[1][rr] * INV2 + b_hz;
    const float r = 1.f / (1.f + expf(-pr));
    const float z = 1.f / (1.f + expf(-pz));
    const float n = tanhf(gi[gr + 2048 + c] + b_in + r * (acc[2][rr] * INV2 + b_hn));
    const size_t o = (size_t)row * Hsz + c;
    const float h = (1.f - z) * n + z * hf_in[o];
    hf_out[o] = h;
    const float hs = h * WSCALE;
    const f16 hb = (f16)hs;
    const f16 lb = (f16)(hs - (float)hb);
    hho[o] = h2u(hb);
    hlo[o] = h2u(lb);
    const size_t o2 = ((size_t)row * Tsz + tstep) * Hsz + c;
    Hph[o2] = h2u(hb);
    Hpl[o2] = h2u(lb);
  }
}

// ============ PRE: P[b][t][l] = h[t] . G[b][l]  (3-pass fp16, per-batch) =======
__global__ __launch_bounds__(256) void k_pre(
    const u16* __restrict__ Hph, const u16* __restrict__ Hpl,
    const u16* __restrict__ Gh, const u16* __restrict__ Gl,
    float* __restrict__ P)
{
  const int b = blockIdx.x;
  const int w = threadIdx.x >> 6, lane = threadIdx.x & 63;
  const int wm = w >> 1, wn = w & 1;
  const int lr = lane & 15, lg = lane >> 4;

  const int t_ = wm * 16 + lr;
  const int l_ = wn * 16 + lr;
  const size_t abase = ((size_t)b * Tsz + t_) * Hsz + lg * 8;
  const size_t bbase = ((size_t)b * Tsz + l_) * Hsz + lg * 8;

  f32x4 acc = {};
  for (int k0 = 0; k0 < Hsz; k0 += 32) {
    const f16x8 ah = ld8h(Hph + abase + k0);
    const f16x8 al = ld8h(Hpl + abase + k0);
    const f16x8 bh = ld8h(Gh + bbase + k0);
    const f16x8 bl = ld8h(Gl + bbase + k0);
    acc = __builtin_amdgcn_mfma_f32_16x16x32_f16(ah, bh, acc, 0, 0, 0);
    acc = __builtin_amdgcn_mfma_f32_16x16x32_f16(ah, bl, acc, 0, 0, 0);
    acc = __builtin_amdgcn_mfma_f32_16x16x32_f16(al, bh, acc, 0, 0, 0);
  }

  #pragma unroll
  for (int rr = 0; rr < 4; ++rr) {
    const int tr = wm * 16 + lg * 4 + rr;
    P[(size_t)b * 1024 + tr * 32 + wn * 16 + lr] = acc[rr] * INV2;
  }
}

// ============ SM: masked softmax + argmax/flag chain, outputs ==================
__global__ __launch_bounds__(64) void k_sm(
    const float* __restrict__ P, const float* __restrict__ c0,
    const u32* __restrict__ valid, float* __restrict__ out)
{
  const int b = blockIdx.x;
  const int l = threadIdx.x;
  const bool act = (l < Lsz);
  const float c0l = act ? c0[b * Lsz + l] : 0.f;
  const u32 vmask = valid[b];
  u32 fl = 0;

  for (int t = 0; t < Tsz; ++t) {
    const float pre = act ? (P[(size_t)b * 1024 + t * 32 + l] + c0l) : 0.f;
    if (act) out[(size_t)b * (Tsz * Lsz) + t * Lsz + l] = pre;
    const u32 ex = fl | ~vmask;
    const bool ok = act && !((ex >> l) & 1u);
    const float v = ok ? pre : -3.4e38f;
    float best = v;
    #pragma unroll
    for (int off = 32; off >= 1; off >>= 1) best = fmaxf(best, __shfl_xor(best, off, 64));
    const unsigned long long msk = __ballot(v == best);
    const int am = __ffsll((long long)msk) - 1;
    const float e = ok ? expf(pre - best) : 0.f;
    float sum = e;
    #pragma unroll
    for (int off = 32; off >= 1; off >>= 1) sum += __shfl_xor(sum, off, 64);
    if (act)
      out[(size_t)Bsz * Tsz * Lsz + (size_t)b * (Tsz * Lsz) + t * Lsz + l] = e / sum;
    fl |= (1u << am);
  }
}

extern "C" void kernel_launch(void* const* d_in, const int* in_sizes, int n_in,
                              void* d_out, int out_size, void* d_ws, size_t ws_size,
                              hipStream_t stream) {
  const float* ih  = (const float*)d_in[0];
  const float* tg  = (const float*)d_in[1];
  const int*   pos = (const int*)d_in[2];
  const float* S   = (const float*)d_in[4];
  const float* wih = (const float*)d_in[5];
  const float* whh = (const float*)d_in[6];
  const float* bih = (const float*)d_in[7];
  const float* bhh = (const float*)d_in[8];
  const float* wlw = (const float*)d_in[9];
  const float* wlb = (const float*)d_in[10];
  float* out = (float*)d_out;

  const size_t NW3 = (size_t)3 * Hsz * Hsz;
  const size_t NW1 = (size_t)Hsz * Hsz;
  const size_t NH  = (size_t)Bsz * Hsz;
  const size_t NPL = ((size_t)Bsz * Tsz + 2) * Hsz;  // padded plane rows

  char* p = (char*)d_ws;
  u16* wihh = (u16*)p; p += NW3 * 2;
  u16* wihl = (u16*)p; p += NW3 * 2;
  u16* whhh = (u16*)p; p += NW3 * 2;
  u16* whhl = (u16*)p; p += NW3 * 2;
  u16* wlt0 = (u16*)p; p += NW1 * 2;
  u16* wlt1 = (u16*)p; p += NW1 * 2;
  float* ring = (float*)p; p += (size_t)8 * Bsz * 3072 * 4;   // 50.3 MB
  u16* Gh  = (u16*)p; p += NPL * 2;
  u16* Gl  = (u16*)p; p += NPL * 2;
  u16* Hph = (u16*)p; p += NPL * 2;
  u16* Hpl = (u16*)p; p += NPL * 2;
  float* P   = (float*)p; p += (size_t)Bsz * 1024 * 4;
  float* c0  = (float*)p; p += (size_t)Bsz * Lsz * 4;
  float* gi0 = (float*)p; p += 3072 * 4;
  float* hfb[2]; u16* hhb[2]; u16* hlb[2];
  hfb[0] = (float*)p; p += NH * 4;
  hfb[1] = (float*)p; p += NH * 4;
  hhb[0] = (u16*)p; p += NH * 2;
  hlb[0] = (u16*)p; p += NH * 2;
  hhb[1] = (u16*)p; p += NH * 2;
  hlb[1] = (u16*)p; p += NH * 2;
  u32* valid = (u32*)p; p += Bsz * 4;

  k_split<<<(int)(NW3 / 4 + 255) / 256, 256, 0, stream>>>(wih, wihh, wihl, (int)(NW3 / 4));
  k_split<<<(int)(NW3 / 4 + 255) / 256, 256, 0, stream>>>(whh, whhh, whhl, (int)(NW3 / 4));
  k_splitT2<<<dim3(32, 32), 256, 0, stream>>>(wlw, wlt0, wlt1);
  k_init<<<Bsz, 256, 0, stream>>>(ih, pos, wlb, hfb[0], hhb[0], hlb[0], c0, valid);
  k_gemv0<<<48, 256, 0, stream>>>(S, wih, gi0);
  // G planes = (ih @ WlT) * 32, fp16 hi/lo
  k_tgemm<0><<<dim3(8, 120), 256, 0, stream>>>(ih, wlt0, wlt1, nullptr, Gh, Gl, Hsz, 0);

  for (int t = 0; t < Tsz; ++t) {
    if (t == 1 || t == 9 || t == 17 || t == 25) {
      const int ns = (t == 25) ? 5 : 8;
      k_tgemm<1><<<dim3(24, ns * 4), 256, 0, stream>>>(tg, wihh, wihl, ring,
                                                       nullptr, nullptr, 3072, t);
    }
    const int ci = t & 1, ni = (t + 1) & 1;
    const float* gip = (t == 0) ? gi0 : (ring + (size_t)(t & 7) * Bsz * 3072);
    k_ghc3<<<512, 256, 0, stream>>>(hhb[ci], hlb[ci], whhh, whhl,
                                    gip, (t == 0) ? 0 : 3072, bih, bhh,
                                    hfb[ci], hfb[ni], hhb[ni], hlb[ni],
                                    Hph, Hpl, t);
  }

  k_pre<<<Bsz, 256, 0, stream>>>(Hph, Hpl, Gh, Gl, P);
  k_sm<<<Bsz, 64, 0, stream>>>(P, c0, valid, out);
}

// Round 17
// 1777.970 us; speedup vs baseline: 1.1988x; 1.0008x over previous
//
#include <hip/hip_runtime.h>

#define Bsz 512
#define Lsz 30
#define Hsz 1024
#define Tsz 30

typedef _Float16 f16;
typedef f16 f16x8 __attribute__((ext_vector_type(8)));
typedef unsigned short u16x8 __attribute__((ext_vector_type(8)));
typedef float  f32x4  __attribute__((ext_vector_type(4)));
typedef unsigned int u32;
typedef unsigned short u16;

#define WSCALE 32.0f
#define INVWS  0.03125f
#define INV2   0.0009765625f   // 1/1024

__device__ __forceinline__ u16 h2u(f16 h) {
  union { f16 h; u16 u; } v; v.h = h; return v.u;
}
__device__ __forceinline__ f16x8 ld8h(const u16* p) {
  return *reinterpret_cast<const f16x8*>(p);
}
__device__ __forceinline__ void stage16(const u16* g, u16* l) {
  __builtin_amdgcn_global_load_lds(
      (const __attribute__((address_space(1))) u32*)g,
      (__attribute__((address_space(3))) u32*)l, 16, 0, 0);
}

// ------- split fp32 -> (hi, lo) fp16 planes, pre-scaled by WSCALE --------------
__global__ __launch_bounds__(256) void k_split(
    const float* __restrict__ src, u16* __restrict__ hi,
    u16* __restrict__ lo, int n4)
{
  const int i = blockIdx.x * 256 + threadIdx.x;
  if (i >= n4) return;
  const float4 v = ((const float4*)src)[i];
  const float f[4] = { v.x * WSCALE, v.y * WSCALE, v.z * WSCALE, v.w * WSCALE };
  u16 h[4], l[4];
  #pragma unroll
  for (int j = 0; j < 4; ++j) {
    const f16 hb = (f16)f[j];
    const f16 lb = (f16)(f[j] - (float)hb);
    h[j] = h2u(hb); l[j] = h2u(lb);
  }
  ((ushort4*)hi)[i] = make_ushort4(h[0], h[1], h[2], h[3]);
  ((ushort4*)lo)[i] = make_ushort4(l[0], l[1], l[2], l[3]);
}

// -------- transpose + scaled fp16 2-plane split: out[k][n] = in[n][k] (Wl) -----
__global__ __launch_bounds__(256) void k_splitT2(
    const float* __restrict__ src, u16* __restrict__ t0, u16* __restrict__ t1)
{
  __shared__ float t[32][33];
  const int tid = threadIdx.x;
  const int bi = blockIdx.x * 32, bj = blockIdx.y * 32;
  const int r = tid >> 3, c4 = (tid & 7) * 4;
  const float4 v = *(const float4*)(src + (size_t)(bi + r) * Hsz + bj + c4);
  t[r][c4] = v.x; t[r][c4 + 1] = v.y; t[r][c4 + 2] = v.z; t[r][c4 + 3] = v.w;
  __syncthreads();
  u16 h[4], l[4];
  #pragma unroll
  for (int i = 0; i < 4; ++i) {
    const float f = t[c4 + i][r] * WSCALE;
    const f16 hb = (f16)f;
    const f16 lb = (f16)(f - (float)hb);
    h[i] = h2u(hb); l[i] = h2u(lb);
  }
  const size_t o = (size_t)(bj + r) * Hsz + bi + c4;
  *(ushort4*)(t0 + o) = make_ushort4(h[0], h[1], h[2], h[3]);
  *(ushort4*)(t1 + o) = make_ushort4(l[0], l[1], l[2], l[3]);
}

// ------ init: h0 = mean_L(ih), scaled h fp16 splits, c0 = Wl_b . ih, valid -----
__global__ __launch_bounds__(256) void k_init(
    const float* __restrict__ ih, const int* __restrict__ pos,
    const float* __restrict__ wlb,
    float* __restrict__ hf, u16* __restrict__ hh,
    u16* __restrict__ hl, float* __restrict__ c0,
    u32* __restrict__ valid)
{
  __shared__ float red[4];
  const int b = blockIdx.x, tid = threadIdx.x;
  const int lane = tid & 63, wid = tid >> 6;
  const float4 wb = ((const float4*)wlb)[tid];
  float s0 = 0.f, s1 = 0.f, s2 = 0.f, s3 = 0.f;
  for (int l = 0; l < Lsz; ++l) {
    const float4 v = ((const float4*)(ih + ((size_t)b * Lsz + l) * Hsz))[tid];
    s0 += v.x; s1 += v.y; s2 += v.z; s3 += v.w;
    float part = v.x * wb.x + v.y * wb.y + v.z * wb.z + v.w * wb.w;
    #pragma unroll
    for (int off = 32; off >= 1; off >>= 1) part += __shfl_xor(part, off, 64);
    if (lane == 0) red[wid] = part;
    __syncthreads();
    if (tid == 0) c0[b * Lsz + l] = red[0] + red[1] + red[2] + red[3];
    __syncthreads();
  }
  const size_t o = (size_t)b * Hsz + tid * 4;
  const float m[4] = { s0 / 30.f, s1 / 30.f, s2 / 30.f, s3 / 30.f };
  *(float4*)(hf + o) = make_float4(m[0], m[1], m[2], m[3]);
  u16 h4[4], l4[4];
  #pragma unroll
  for (int j = 0; j < 4; ++j) {
    const float hs = m[j] * WSCALE;
    const f16 hb = (f16)hs;
    const f16 lb = (f16)(hs - (float)hb);
    h4[j] = h2u(hb); l4[j] = h2u(lb);
  }
  *(ushort4*)(hh + o) = make_ushort4(h4[0], h4[1], h4[2], h4[3]);
  *(ushort4*)(hl + o) = make_ushort4(l4[0], l4[1], l4[2], l4[3]);
  if (tid == 0) {
    int ss = 0;
    for (int l = 0; l < Lsz; ++l) ss += (pos[b * Lsz + l] != -1) ? 1 : 0;
    valid[b] = (ss >= 32) ? 0xFFFFFFFFu : ((1u << ss) - 1u);
  }
}

// ---------------- gi0 = S @ W_ih^T (fp32 GEMV, 3072 outputs) -------------------
__global__ __launch_bounds__(256) void k_gemv0(
    const float* __restrict__ S, const float* __restrict__ wih,
    float* __restrict__ gi0)
{
  const int n = blockIdx.x * 64 + (threadIdx.x >> 2);
  const int part = threadIdx.x & 3;
  const float4* s4 = (const float4*)S + part * 64;
  const float4* w4 = (const float4*)(wih + (size_t)n * Hsz) + part * 64;
  float s = 0.f;
  #pragma unroll 8
  for (int i = 0; i < 64; ++i) {
    const float4 a = s4[i], b = w4[i];
    s = fmaf(a.x, b.x, s); s = fmaf(a.y, b.y, s);
    s = fmaf(a.z, b.z, s); s = fmaf(a.w, b.w, s);
  }
  s += __shfl_xor(s, 1, 64);
  s += __shfl_xor(s, 2, 64);
  if (part == 0) gi0[n] = s;
}

// ============ 3-pass fp16 GEMM, A reg-split from fp32, dbuf LDS, XCD swizzle ===
// MODE1 (GI): A-row remap into tgt, fp32 C into 8-slot ring, acc*INVWS.
// MODE0 (G):  plain A rows; acc (=32*G) split into fp16 planes Ch/Cl.
template<int MODE>
__global__ __launch_bounds__(256) void k_tgemm(
    const float* __restrict__ Afp,
    const u16* __restrict__ Bh, const u16* __restrict__ Bl,
    float* __restrict__ C, u16* __restrict__ Ch, u16* __restrict__ Cl,
    int ldc, int t0)
{
  constexpr int oAh = 0, oAl = 4096, oBh = 8192, oBl = 12288;
  __shared__ u16 lds[2][16384];

  const int tid = threadIdx.x;
  const int w = tid >> 6, lane = tid & 63;
  const int wm = w >> 1, wn = w & 1;
  const int lr = lane & 15, lg = lane >> 4;

  const int nwg = gridDim.x * gridDim.y;
  int lin = blockIdx.y * gridDim.x + blockIdx.x;
  lin = (lin & 7) * (nwg >> 3) + (lin >> 3);
  const int bm = (lin / gridDim.x) * 128, bn = (lin % gridDim.x) * 128;

  const int ar = tid & 127, kh = tid >> 7;
  long arow;
  if (MODE == 1) arow = (long)((bm + ar) & 511) * Tsz + (t0 - 1) + ((bm + ar) >> 9);
  else           arow = bm + ar;
  const float* aptr = Afp + arow * Hsz + kh * 16;
  const int awo0 = (ar >> 4) * 512 + ((ar & 15) + 32 * kh) * 8;

  const u16* gpB[4]; int bwo[4];
  #pragma unroll
  for (int i = 0; i < 4; ++i) {
    const int cid = (w << 2) | i;
    const u16* base; int g, off;
    if (cid < 8) { base = Bh; g = cid;     off = oBh + g * 512; }
    else         { base = Bl; g = cid - 8; off = oBl + g * 512; }
    gpB[i] = base + (size_t)(bn + g * 16 + lr) * Hsz + lg * 8;
    bwo[i] = off;
  }

  float4 areg[4];
  #define LOAD_A() { _Pragma("unroll") for (int i = 0; i < 4; ++i) areg[i] = ((const float4*)aptr)[i]; aptr += 32; }
  #define STAGE_B(buf) { _Pragma("unroll") for (int i = 0; i < 4; ++i) { stage16(gpB[i], &lds[buf][bwo[i]]); gpB[i] += 32; } }
  #define WRITE_A(buf) { \
    u16x8 h0v, h1v, l0v, l1v; \
    _Pragma("unroll") for (int i = 0; i < 4; ++i) { \
      const float f[4] = { areg[i].x, areg[i].y, areg[i].z, areg[i].w }; \
      _Pragma("unroll") for (int c = 0; c < 4; ++c) { \
        const int j = 4 * i + c; \
        const f16 hb = (f16)f[c]; \
        const f16 lb = (f16)(f[c] - (float)hb); \
        if (j < 8) { h0v[j] = h2u(hb); l0v[j] = h2u(lb); } \
        else       { h1v[j - 8] = h2u(hb); l1v[j - 8] = h2u(lb); } \
      } \
    } \
    *(u16x8*)&lds[buf][oAh + awo0]       = h0v; \
    *(u16x8*)&lds[buf][oAh + awo0 + 128] = h1v; \
    *(u16x8*)&lds[buf][oAl + awo0]       = l0v; \
    *(u16x8*)&lds[buf][oAl + awo0 + 128] = l1v; }

  f32x4 acc[4][4] = {};

  LOAD_A();
  STAGE_B(0);
  WRITE_A(0);
  __syncthreads();

  for (int ks = 0; ks < 32; ++ks) {
    const int cur = ks & 1;
    if (ks < 31) { STAGE_B(cur ^ 1); LOAD_A(); }
    {
      const u16* L = &lds[cur][0];
      f16x8 a_h[4], a_l[4], b_h[4], b_l[4];
      #pragma unroll
      for (int m = 0; m < 4; ++m) {
        const int g = wm * 4 + m;
        a_h[m] = ld8h(L + oAh + g * 512 + lane * 8);
        a_l[m] = ld8h(L + oAl + g * 512 + lane * 8);
      }
      #pragma unroll
      for (int n = 0; n < 4; ++n) {
        const int g = wn * 4 + n;
        b_h[n] = ld8h(L + oBh + g * 512 + lane * 8);
        b_l[n] = ld8h(L + oBl + g * 512 + lane * 8);
      }
      #pragma unroll
      for (int m = 0; m < 4; ++m)
        #pragma unroll
        for (int n = 0; n < 4; ++n) {
          acc[m][n] = __builtin_amdgcn_mfma_f32_16x16x32_f16(a_h[m], b_h[n], acc[m][n], 0, 0, 0);
          acc[m][n] = __builtin_amdgcn_mfma_f32_16x16x32_f16(a_h[m], b_l[n], acc[m][n], 0, 0, 0);
          acc[m][n] = __builtin_amdgcn_mfma_f32_16x16x32_f16(a_l[m], b_h[n], acc[m][n], 0, 0, 0);
        }
    }
    __syncthreads();
    if (ks < 31) { WRITE_A(cur ^ 1); __syncthreads(); }
  }

  #pragma unroll
  for (int n = 0; n < 4; ++n) {
    const int col = bn + wn * 64 + n * 16 + lr;
    #pragma unroll
    for (int m = 0; m < 4; ++m) {
      #pragma unroll
      for (int rr = 0; rr < 4; ++rr) {
        const int row = bm + wm * 64 + m * 16 + lg * 4 + rr;
        if (MODE == 1) {
          const int slot = (t0 + (row >> 9)) & 7;
          C[((size_t)slot * Bsz + (row & 511)) * 3072 + col] = acc[m][n][rr] * INVWS;
        } else {
          const float v = acc[m][n][rr];                // = 32 * G
          const f16 hb = (f16)v;
          const f16 lb = (f16)(v - (float)hb);
          Ch[(size_t)row * ldc + col] = h2u(hb);
          Cl[(size_t)row * ldc + col] = h2u(lb);
        }
      }
    }
  }
  #undef LOAD_A
  #undef STAGE_B
  #undef WRITE_A
}

// ============ ghc3: gh-GEMM (3 gates) + GRU combine, 64x16 tiles, grid 512 =====
// 256 thr (4 waves), wave w = row-frag. LDS: A 8 chunks + W 6 chunks, dbuf 28KB.
__global__ __launch_bounds__(256) void k_ghc3(
    const u16* __restrict__ Hh, const u16* __restrict__ Hl,
    const u16* __restrict__ WHh, const u16* __restrict__ WHl,
    const float* __restrict__ gi, int gi_rs,
    const float* __restrict__ bih, const float* __restrict__ bhh,
    const float* __restrict__ hf_in, float* __restrict__ hf_out,
    u16* __restrict__ hho, u16* __restrict__ hlo,
    u16* __restrict__ Hph, u16* __restrict__ Hpl, int tstep)
{
  constexpr int oAh = 0, oAl = 2048, oWh = 4096, oWl = 5632;
  __shared__ u16 lds[2][7168];

  const int bn = (blockIdx.x & 63) * 16, bm = (blockIdx.x >> 6) * 64;
  const int tid = threadIdx.x;
  const int w = tid >> 6, lane = tid & 63;
  const int lr = lane & 15, lg = lane >> 4;

  // 14 chunks over 4 waves: wave w takes cid = w, w+4, w+8, (w<2: w+12)
  const u16* gp[4]; int ldso[4];
  const int nch = (w < 2) ? 4 : 3;
  #pragma unroll
  for (int i = 0; i < 4; ++i) {
    const int cid = w + 4 * i;
    if (cid >= 14) break;
    const u16* base; long row; int off;
    if (cid < 4)       { const int g = cid;      row = bm + g * 16 + lr;   base = Hh;  off = oAh + g * 512; }
    else if (cid < 8)  { const int g = cid - 4;  row = bm + g * 16 + lr;   base = Hl;  off = oAl + g * 512; }
    else if (cid < 11) { const int g = cid - 8;  row = g * 1024 + bn + lr; base = WHh; off = oWh + g * 512; }
    else               { const int g = cid - 11; row = g * 1024 + bn + lr; base = WHl; off = oWl + g * 512; }
    gp[i] = base + row * Hsz + lg * 8;
    ldso[i] = off;
  }

  f32x4 acc[3] = {};

  for (int i = 0; i < nch; ++i) { stage16(gp[i], &lds[0][ldso[i]]); gp[i] += 32; }
  __syncthreads();

  for (int ks = 0; ks < 32; ++ks) {
    const int cur = ks & 1;
    if (ks < 31) {
      for (int i = 0; i < nch; ++i) { stage16(gp[i], &lds[cur ^ 1][ldso[i]]); gp[i] += 32; }
    }
    const u16* L = &lds[cur][0];
    const f16x8 ah = ld8h(L + oAh + w * 512 + lane * 8);
    const f16x8 al = ld8h(L + oAl + w * 512 + lane * 8);
    #pragma unroll
    for (int gt = 0; gt < 3; ++gt) {
      const f16x8 bh = ld8h(L + oWh + gt * 512 + lane * 8);
      const f16x8 bl = ld8h(L + oWl + gt * 512 + lane * 8);
      acc[gt] = __builtin_amdgcn_mfma_f32_16x16x32_f16(ah, bh, acc[gt], 0, 0, 0);
      acc[gt] = __builtin_amdgcn_mfma_f32_16x16x32_f16(ah, bl, acc[gt], 0, 0, 0);
      acc[gt] = __builtin_amdgcn_mfma_f32_16x16x32_f16(al, bh, acc[gt], 0, 0, 0);
    }
    __syncthreads();
  }

  const int c = bn + lr;
  const float b_ir = bih[c], b_iz = bih[1024 + c], b_in = bih[2048 + c];
  const float b_hr = bhh[c], b_hz = bhh[1024 + c], b_hn = bhh[2048 + c];
  #pragma unroll
  for (int rr = 0; rr < 4; ++rr) {
    const int row = bm + w * 16 + lg * 4 + rr;
    const size_t gr = (size_t)row * gi_rs;
    const float pr = gi[gr + c]        + b_ir + acc[0][rr] * INV2 + b_hr;
    const float pz = gi[gr + 1024 + c] + b_iz + acc[1][rr] * INV2 + b_hz;
    const float r = 1.f / (1.f + expf(-pr));
    const float z = 1.f / (1.f + expf(-pz));
    const float n = tanhf(gi[gr + 2048 + c] + b_in + r * (acc[2][rr] * INV2 + b_hn));
    const size_t o = (size_t)row * Hsz + c;
    const float h = (1.f - z) * n + z * hf_in[o];
    hf_out[o] = h;
    const float hs = h * WSCALE;
    const f16 hb = (f16)hs;
    const f16 lb = (f16)(hs - (float)hb);
    hho[o] = h2u(hb);
    hlo[o] = h2u(lb);
    const size_t o2 = ((size_t)row * Tsz + tstep) * Hsz + c;
    Hph[o2] = h2u(hb);
    Hpl[o2] = h2u(lb);
  }
}

// ============ PRE: P[b][t][l] = h[t] . G[b][l]  (3-pass fp16, per-batch) =======
__global__ __launch_bounds__(256) void k_pre(
    const u16* __restrict__ Hph, const u16* __restrict__ Hpl,
    const u16* __restrict__ Gh, const u16* __restrict__ Gl,
    float* __restrict__ P)
{
  const int b = blockIdx.x;
  const int w = threadIdx.x >> 6, lane = threadIdx.x & 63;
  const int wm = w >> 1, wn = w & 1;
  const int lr = lane & 15, lg = lane >> 4;

  const int t_ = wm * 16 + lr;
  const int l_ = wn * 16 + lr;
  const size_t abase = ((size_t)b * Tsz + t_) * Hsz + lg * 8;
  const size_t bbase = ((size_t)b * Tsz + l_) * Hsz + lg * 8;

  f32x4 acc = {};
  for (int k0 = 0; k0 < Hsz; k0 += 32) {
    const f16x8 ah = ld8h(Hph + abase + k0);
    const f16x8 al = ld8h(Hpl + abase + k0);
    const f16x8 bh = ld8h(Gh + bbase + k0);
    const f16x8 bl = ld8h(Gl + bbase + k0);
    acc = __builtin_amdgcn_mfma_f32_16x16x32_f16(ah, bh, acc, 0, 0, 0);
    acc = __builtin_amdgcn_mfma_f32_16x16x32_f16(ah, bl, acc, 0, 0, 0);
    acc = __builtin_amdgcn_mfma_f32_16x16x32_f16(al, bh, acc, 0, 0, 0);
  }

  #pragma unroll
  for (int rr = 0; rr < 4; ++rr) {
    const int tr = wm * 16 + lg * 4 + rr;
    P[(size_t)b * 1024 + tr * 32 + wn * 16 + lr] = acc[rr] * INV2;
  }
}

// ============ SM: masked softmax + argmax/flag chain, outputs ==================
__global__ __launch_bounds__(64) void k_sm(
    const float* __restrict__ P, const float* __restrict__ c0,
    const u32* __restrict__ valid, float* __restrict__ out)
{
  const int b = blockIdx.x;
  const int l = threadIdx.x;
  const bool act = (l < Lsz);
  const float c0l = act ? c0[b * Lsz + l] : 0.f;
  const u32 vmask = valid[b];
  u32 fl = 0;

  for (int t = 0; t < Tsz; ++t) {
    const float pre = act ? (P[(size_t)b * 1024 + t * 32 + l] + c0l) : 0.f;
    if (act) out[(size_t)b * (Tsz * Lsz) + t * Lsz + l] = pre;
    const u32 ex = fl | ~vmask;
    const bool ok = act && !((ex >> l) & 1u);
    const float v = ok ? pre : -3.4e38f;
    float best = v;
    #pragma unroll
    for (int off = 32; off >= 1; off >>= 1) best = fmaxf(best, __shfl_xor(best, off, 64));
    const unsigned long long msk = __ballot(v == best);
    const int am = __ffsll((long long)msk) - 1;
    const float e = ok ? expf(pre - best) : 0.f;
    float sum = e;
    #pragma unroll
    for (int off = 32; off >= 1; off >>= 1) sum += __shfl_xor(sum, off, 64);
    if (act)
      out[(size_t)Bsz * Tsz * Lsz + (size_t)b * (Tsz * Lsz) + t * Lsz + l] = e / sum;
    fl |= (1u << am);
  }
}

extern "C" void kernel_launch(void* const* d_in, const int* in_sizes, int n_in,
                              void* d_out, int out_size, void* d_ws, size_t ws_size,
                              hipStream_t stream) {
  const float* ih  = (const float*)d_in[0];
  const float* tg  = (const float*)d_in[1];
  const int*   pos = (const int*)d_in[2];
  const float* S   = (const float*)d_in[4];
  const float* wih = (const float*)d_in[5];
  const float* whh = (const float*)d_in[6];
  const float* bih = (const float*)d_in[7];
  const float* bhh = (const float*)d_in[8];
  const float* wlw = (const float*)d_in[9];
  const float* wlb = (const float*)d_in[10];
  float* out = (float*)d_out;

  const size_t NW3 = (size_t)3 * Hsz * Hsz;
  const size_t NW1 = (size_t)Hsz * Hsz;
  const size_t NH  = (size_t)Bsz * Hsz;
  const size_t NPL = ((size_t)Bsz * Tsz + 2) * Hsz;  // padded plane rows

  char* p = (char*)d_ws;
  u16* wihh = (u16*)p; p += NW3 * 2;
  u16* wihl = (u16*)p; p += NW3 * 2;
  u16* whhh = (u16*)p; p += NW3 * 2;
  u16* whhl = (u16*)p; p += NW3 * 2;
  u16* wlt0 = (u16*)p; p += NW1 * 2;
  u16* wlt1 = (u16*)p; p += NW1 * 2;
  float* ring = (float*)p; p += (size_t)8 * Bsz * 3072 * 4;   // 50.3 MB
  u16* Gh  = (u16*)p; p += NPL * 2;
  u16* Gl  = (u16*)p; p += NPL * 2;
  u16* Hph = (u16*)p; p += NPL * 2;
  u16* Hpl = (u16*)p; p += NPL * 2;
  float* P   = (float*)p; p += (size_t)Bsz * 1024 * 4;
  float* c0  = (float*)p; p += (size_t)Bsz * Lsz * 4;
  float* gi0 = (float*)p; p += 3072 * 4;
  float* hfb[2]; u16* hhb[2]; u16* hlb[2];
  hfb[0] = (float*)p; p += NH * 4;
  hfb[1] = (float*)p; p += NH * 4;
  hhb[0] = (u16*)p; p += NH * 2;
  hlb[0] = (u16*)p; p += NH * 2;
  hhb[1] = (u16*)p; p += NH * 2;
  hlb[1] = (u16*)p; p += NH * 2;
  u32* valid = (u32*)p; p += Bsz * 4;

  k_split<<<(int)(NW3 / 4 + 255) / 256, 256, 0, stream>>>(wih, wihh, wihl, (int)(NW3 / 4));
  k_split<<<(int)(NW3 / 4 + 255) / 256, 256, 0, stream>>>(whh, whhh, whhl, (int)(NW3 / 4));
  k_splitT2<<<dim3(32, 32), 256, 0, stream>>>(wlw, wlt0, wlt1);
  k_init<<<Bsz, 256, 0, stream>>>(ih, pos, wlb, hfb[0], hhb[0], hlb[0], c0, valid);
  k_gemv0<<<48, 256, 0, stream>>>(S, wih, gi0);
  // G planes = (ih @ WlT) * 32, fp16 hi/lo
  k_tgemm<0><<<dim3(8, 120), 256, 0, stream>>>(ih, wlt0, wlt1, nullptr, Gh, Gl, Hsz, 0);

  for (int t = 0; t < Tsz; ++t) {
    if (t == 1 || t == 9 || t == 17 || t == 25) {
      const int ns = (t == 25) ? 5 : 8;
      k_tgemm<1><<<dim3(24, ns * 4), 256, 0, stream>>>(tg, wihh, wihl, ring,
                                                       nullptr, nullptr, 3072, t);
    }
    const int ci = t & 1, ni = (t + 1) & 1;
    const float* gip = (t == 0) ? gi0 : (ring + (size_t)(t & 7) * Bsz * 3072);
    k_ghc3<<<512, 256, 0, stream>>>(hhb[ci], hlb[ci], whhh, whhl,
                                    gip, (t == 0) ? 0 : 3072, bih, bhh,
                                    hfb[ci], hfb[ni], hhb[ni], hlb[ni],
                                    Hph, Hpl, t);
  }

  k_pre<<<Bsz, 256, 0, stream>>>(Hph, Hpl, Gh, Gl, P);
  k_sm<<<Bsz, 64, 0, stream>>>(P, c0, valid, out);
}

// Round 18
// 1473.761 us; speedup vs baseline: 1.4462x; 1.2064x over previous
//
#include <hip/hip_runtime.h>

#define Bsz 512
#define Lsz 30
#define Hsz 1024
#define Tsz 30

typedef _Float16 f16;
typedef f16 f16x8 __attribute__((ext_vector_type(8)));
typedef unsigned short u16x8 __attribute__((ext_vector_type(8)));
typedef float  f32x4  __attribute__((ext_vector_type(4)));
typedef unsigned int u32;
typedef unsigned short u16;

#define WSCALE 32.0f
#define INVWS  0.03125f
#define INV2   0.0009765625f   // 1/1024

__device__ __forceinline__ u16 h2u(f16 h) {
  union { f16 h; u16 u; } v; v.h = h; return v.u;
}
__device__ __forceinline__ f16x8 ld8h(const u16* p) {
  return *reinterpret_cast<const f16x8*>(p);
}
__device__ __forceinline__ void stage16(const u16* g, u16* l) {
  __builtin_amdgcn_global_load_lds(
      (const __attribute__((address_space(1))) u32*)g,
      (__attribute__((address_space(3))) u32*)l, 16, 0, 0);
}

// ------- split fp32 -> (hi, lo) fp16 planes, pre-scaled by WSCALE --------------
__global__ __launch_bounds__(256) void k_split(
    const float* __restrict__ src, u16* __restrict__ hi,
    u16* __restrict__ lo, int n4)
{
  const int i = blockIdx.x * 256 + threadIdx.x;
  if (i >= n4) return;
  const float4 v = ((const float4*)src)[i];
  const float f[4] = { v.x * WSCALE, v.y * WSCALE, v.z * WSCALE, v.w * WSCALE };
  u16 h[4], l[4];
  #pragma unroll
  for (int j = 0; j < 4; ++j) {
    const f16 hb = (f16)f[j];
    const f16 lb = (f16)(f[j] - (float)hb);
    h[j] = h2u(hb); l[j] = h2u(lb);
  }
  ((ushort4*)hi)[i] = make_ushort4(h[0], h[1], h[2], h[3]);
  ((ushort4*)lo)[i] = make_ushort4(l[0], l[1], l[2], l[3]);
}

// -------- transpose + scaled fp16 2-plane split: out[k][n] = in[n][k] (Wl) -----
__global__ __launch_bounds__(256) void k_splitT2(
    const float* __restrict__ src, u16* __restrict__ t0, u16* __restrict__ t1)
{
  __shared__ float t[32][33];
  const int tid = threadIdx.x;
  const int bi = blockIdx.x * 32, bj = blockIdx.y * 32;
  const int r = tid >> 3, c4 = (tid & 7) * 4;
  const float4 v = *(const float4*)(src + (size_t)(bi + r) * Hsz + bj + c4);
  t[r][c4] = v.x; t[r][c4 + 1] = v.y; t[r][c4 + 2] = v.z; t[r][c4 + 3] = v.w;
  __syncthreads();
  u16 h[4], l[4];
  #pragma unroll
  for (int i = 0; i < 4; ++i) {
    const float f = t[c4 + i][r] * WSCALE;
    const f16 hb = (f16)f;
    const f16 lb = (f16)(f - (float)hb);
    h[i] = h2u(hb); l[i] = h2u(lb);
  }
  const size_t o = (size_t)(bj + r) * Hsz + bi + c4;
  *(ushort4*)(t0 + o) = make_ushort4(h[0], h[1], h[2], h[3]);
  *(ushort4*)(t1 + o) = make_ushort4(l[0], l[1], l[2], l[3]);
}

// ------ init: h0 = mean_L(ih), scaled h fp16 splits, c0 = Wl_b . ih, valid -----
__global__ __launch_bounds__(256) void k_init(
    const float* __restrict__ ih, const int* __restrict__ pos,
    const float* __restrict__ wlb,
    float* __restrict__ hf, u16* __restrict__ hh,
    u16* __restrict__ hl, float* __restrict__ c0,
    u32* __restrict__ valid)
{
  __shared__ float red[4];
  const int b = blockIdx.x, tid = threadIdx.x;
  const int lane = tid & 63, wid = tid >> 6;
  const float4 wb = ((const float4*)wlb)[tid];
  float s0 = 0.f, s1 = 0.f, s2 = 0.f, s3 = 0.f;
  for (int l = 0; l < Lsz; ++l) {
    const float4 v = ((const float4*)(ih + ((size_t)b * Lsz + l) * Hsz))[tid];
    s0 += v.x; s1 += v.y; s2 += v.z; s3 += v.w;
    float part = v.x * wb.x + v.y * wb.y + v.z * wb.z + v.w * wb.w;
    #pragma unroll
    for (int off = 32; off >= 1; off >>= 1) part += __shfl_xor(part, off, 64);
    if (lane == 0) red[wid] = part;
    __syncthreads();
    if (tid == 0) c0[b * Lsz + l] = red[0] + red[1] + red[2] + red[3];
    __syncthreads();
  }
  const size_t o = (size_t)b * Hsz + tid * 4;
  const float m[4] = { s0 / 30.f, s1 / 30.f, s2 / 30.f, s3 / 30.f };
  *(float4*)(hf + o) = make_float4(m[0], m[1], m[2], m[3]);
  u16 h4[4], l4[4];
  #pragma unroll
  for (int j = 0; j < 4; ++j) {
    const float hs = m[j] * WSCALE;
    const f16 hb = (f16)hs;
    const f16 lb = (f16)(hs - (float)hb);
    h4[j] = h2u(hb); l4[j] = h2u(lb);
  }
  *(ushort4*)(hh + o) = make_ushort4(h4[0], h4[1], h4[2], h4[3]);
  *(ushort4*)(hl + o) = make_ushort4(l4[0], l4[1], l4[2], l4[3]);
  if (tid == 0) {
    int ss = 0;
    for (int l = 0; l < Lsz; ++l) ss += (pos[b * Lsz + l] != -1) ? 1 : 0;
    valid[b] = (ss >= 32) ? 0xFFFFFFFFu : ((1u << ss) - 1u);
  }
}

// ---------------- gi0 = S @ W_ih^T (fp32 GEMV, 3072 outputs) -------------------
__global__ __launch_bounds__(256) void k_gemv0(
    const float* __restrict__ S, const float* __restrict__ wih,
    float* __restrict__ gi0)
{
  const int n = blockIdx.x * 64 + (threadIdx.x >> 2);
  const int part = threadIdx.x & 3;
  const float4* s4 = (const float4*)S + part * 64;
  const float4* w4 = (const float4*)(wih + (size_t)n * Hsz) + part * 64;
  float s = 0.f;
  #pragma unroll 8
  for (int i = 0; i < 64; ++i) {
    const float4 a = s4[i], b = w4[i];
    s = fmaf(a.x, b.x, s); s = fmaf(a.y, b.y, s);
    s = fmaf(a.z, b.z, s); s = fmaf(a.w, b.w, s);
  }
  s += __shfl_xor(s, 1, 64);
  s += __shfl_xor(s, 2, 64);
  if (part == 0) gi0[n] = s;
}

// ============ 3-pass fp16 GEMM, A reg-split from fp32, dbuf LDS, XCD swizzle ===
// MODE1 (GI): A-row remap into tgt, fp32 C into 8-slot ring, acc*INVWS.
// MODE0 (G):  plain A rows; acc (=32*G) split into fp16 planes Ch/Cl.
template<int MODE>
__global__ __launch_bounds__(256) void k_tgemm(
    const float* __restrict__ Afp,
    const u16* __restrict__ Bh, const u16* __restrict__ Bl,
    float* __restrict__ C, u16* __restrict__ Ch, u16* __restrict__ Cl,
    int ldc, int t0)
{
  constexpr int oAh = 0, oAl = 4096, oBh = 8192, oBl = 12288;
  __shared__ u16 lds[2][16384];

  const int tid = threadIdx.x;
  const int w = tid >> 6, lane = tid & 63;
  const int wm = w >> 1, wn = w & 1;
  const int lr = lane & 15, lg = lane >> 4;

  const int nwg = gridDim.x * gridDim.y;
  int lin = blockIdx.y * gridDim.x + blockIdx.x;
  lin = (lin & 7) * (nwg >> 3) + (lin >> 3);
  const int bm = (lin / gridDim.x) * 128, bn = (lin % gridDim.x) * 128;

  const int ar = tid & 127, kh = tid >> 7;
  long arow;
  if (MODE == 1) arow = (long)((bm + ar) & 511) * Tsz + (t0 - 1) + ((bm + ar) >> 9);
  else           arow = bm + ar;
  const float* aptr = Afp + arow * Hsz + kh * 16;
  const int awo0 = (ar >> 4) * 512 + ((ar & 15) + 32 * kh) * 8;

  const u16* gpB[4]; int bwo[4];
  #pragma unroll
  for (int i = 0; i < 4; ++i) {
    const int cid = (w << 2) | i;
    const u16* base; int g, off;
    if (cid < 8) { base = Bh; g = cid;     off = oBh + g * 512; }
    else         { base = Bl; g = cid - 8; off = oBl + g * 512; }
    gpB[i] = base + (size_t)(bn + g * 16 + lr) * Hsz + lg * 8;
    bwo[i] = off;
  }

  float4 areg[4];
  #define LOAD_A() { _Pragma("unroll") for (int i = 0; i < 4; ++i) areg[i] = ((const float4*)aptr)[i]; aptr += 32; }
  #define STAGE_B(buf) { _Pragma("unroll") for (int i = 0; i < 4; ++i) { stage16(gpB[i], &lds[buf][bwo[i]]); gpB[i] += 32; } }
  #define WRITE_A(buf) { \
    u16x8 h0v, h1v, l0v, l1v; \
    _Pragma("unroll") for (int i = 0; i < 4; ++i) { \
      const float f[4] = { areg[i].x, areg[i].y, areg[i].z, areg[i].w }; \
      _Pragma("unroll") for (int c = 0; c < 4; ++c) { \
        const int j = 4 * i + c; \
        const f16 hb = (f16)f[c]; \
        const f16 lb = (f16)(f[c] - (float)hb); \
        if (j < 8) { h0v[j] = h2u(hb); l0v[j] = h2u(lb); } \
        else       { h1v[j - 8] = h2u(hb); l1v[j - 8] = h2u(lb); } \
      } \
    } \
    *(u16x8*)&lds[buf][oAh + awo0]       = h0v; \
    *(u16x8*)&lds[buf][oAh + awo0 + 128] = h1v; \
    *(u16x8*)&lds[buf][oAl + awo0]       = l0v; \
    *(u16x8*)&lds[buf][oAl + awo0 + 128] = l1v; }

  f32x4 acc[4][4] = {};

  LOAD_A();
  STAGE_B(0);
  WRITE_A(0);
  __syncthreads();

  for (int ks = 0; ks < 32; ++ks) {
    const int cur = ks & 1;
    if (ks < 31) { STAGE_B(cur ^ 1); LOAD_A(); }
    {
      const u16* L = &lds[cur][0];
      f16x8 a_h[4], a_l[4], b_h[4], b_l[4];
      #pragma unroll
      for (int m = 0; m < 4; ++m) {
        const int g = wm * 4 + m;
        a_h[m] = ld8h(L + oAh + g * 512 + lane * 8);
        a_l[m] = ld8h(L + oAl + g * 512 + lane * 8);
      }
      #pragma unroll
      for (int n = 0; n < 4; ++n) {
        const int g = wn * 4 + n;
        b_h[n] = ld8h(L + oBh + g * 512 + lane * 8);
        b_l[n] = ld8h(L + oBl + g * 512 + lane * 8);
      }
      #pragma unroll
      for (int m = 0; m < 4; ++m)
        #pragma unroll
        for (int n = 0; n < 4; ++n) {
          acc[m][n] = __builtin_amdgcn_mfma_f32_16x16x32_f16(a_h[m], b_h[n], acc[m][n], 0, 0, 0);
          acc[m][n] = __builtin_amdgcn_mfma_f32_16x16x32_f16(a_h[m], b_l[n], acc[m][n], 0, 0, 0);
          acc[m][n] = __builtin_amdgcn_mfma_f32_16x16x32_f16(a_l[m], b_h[n], acc[m][n], 0, 0, 0);
        }
    }
    __syncthreads();
    if (ks < 31) { WRITE_A(cur ^ 1); __syncthreads(); }
  }

  #pragma unroll
  for (int n = 0; n < 4; ++n) {
    const int col = bn + wn * 64 + n * 16 + lr;
    #pragma unroll
    for (int m = 0; m < 4; ++m) {
      #pragma unroll
      for (int rr = 0; rr < 4; ++rr) {
        const int row = bm + wm * 64 + m * 16 + lg * 4 + rr;
        if (MODE == 1) {
          const int slot = (t0 + (row >> 9)) & 7;
          C[((size_t)slot * Bsz + (row & 511)) * 3072 + col] = acc[m][n][rr] * INVWS;
        } else {
          const float v = acc[m][n][rr];                // = 32 * G
          const f16 hb = (f16)v;
          const f16 lb = (f16)(v - (float)hb);
          Ch[(size_t)row * ldc + col] = h2u(hb);
          Cl[(size_t)row * ldc + col] = h2u(lb);
        }
      }
    }
  }
  #undef LOAD_A
  #undef STAGE_B
  #undef WRITE_A
}

// ============ ghc: gh-GEMM (3 gates) + GRU combine, 8 waves, 64x32 =============
// COUNTED-VMCNT pipeline: 3 LDS buffers, 2-deep prefetch, raw s_barrier.
// Per iter: stage buf[k+2] -> vmcnt(2*nch) -> barrier -> ds_read+MFMA ->
// lgkmcnt(0)+sched_barrier -> barrier. Loads get 2 iterations of latency slack.
__global__ __launch_bounds__(512) void k_ghc(
    const u16* __restrict__ Hh, const u16* __restrict__ Hl,
    const u16* __restrict__ Wh, const u16* __restrict__ Wl,
    const float* __restrict__ gi, int gi_rs,
    const float* __restrict__ bih, const float* __restrict__ bhh,
    const float* __restrict__ hf_in, float* __restrict__ hf_out,
    u16* __restrict__ hho, u16* __restrict__ hlo,
    u16* __restrict__ Hph, u16* __restrict__ Hpl, int tstep)
{
  constexpr int oAh = 0, oAl = 2048, oBh = 4096, oBl = 7168;
  __shared__ u16 lds[3][10240];   // 60 KB

  const int bn = (blockIdx.x & 31) * 32, bm = (blockIdx.x >> 5) * 64;
  const int tid = threadIdx.x;
  const int w = tid >> 6, lane = tid & 63;
  const int wm = w >> 1, wn = w & 1;
  const int lr = lane & 15, lg = lane >> 4;

  // 20 chunks over 8 waves: wave w takes cid = w, w+8, (w<4: w+16)
  const u16* gp[3]; int ldso[3];
  const int nch = (w < 4) ? 3 : 2;
  #pragma unroll
  for (int i = 0; i < 3; ++i) {
    const int cid = w + 8 * i;
    if (cid >= 20) break;
    const u16* base; long row; int off;
    if (cid < 4)       { const int g = cid;      row = bm + g * 16 + lr;                         base = Hh; off = oAh + g * 512; }
    else if (cid < 8)  { const int g = cid - 4;  row = bm + g * 16 + lr;                         base = Hl; off = oAl + g * 512; }
    else if (cid < 14) { const int g = cid - 8;  row = (g >> 1) * 1024 + bn + (g & 1) * 16 + lr; base = Wh; off = oBh + g * 512; }
    else               { const int g = cid - 14; row = (g >> 1) * 1024 + bn + (g & 1) * 16 + lr; base = Wl; off = oBl + g * 512; }
    gp[i] = base + row * Hsz + lg * 8;
    ldso[i] = off;
  }

  f32x4 acc[3] = {};

  // prologue: stage buf0 (k=0) and buf1 (k=1)
  for (int i = 0; i < nch; ++i) { stage16(gp[i], &lds[0][ldso[i]]); gp[i] += 32; }
  for (int i = 0; i < nch; ++i) { stage16(gp[i], &lds[1][ldso[i]]); gp[i] += 32; }

  int cur = 0;
  for (int ks = 0; ks < 32; ++ks) {
    if (ks < 30) {
      const int nxt2 = (cur >= 1) ? cur - 1 : cur + 2;   // (cur+2)%3
      for (int i = 0; i < nch; ++i) { stage16(gp[i], &lds[nxt2][ldso[i]]); gp[i] += 32; }
      // wait: buf[cur]'s loads (issued 2 iters ago) retired; 2*nch stay in flight
      if (w < 4) asm volatile("s_waitcnt vmcnt(6)" ::: "memory");
      else       asm volatile("s_waitcnt vmcnt(4)" ::: "memory");
    } else if (ks == 30) {
      if (w < 4) asm volatile("s_waitcnt vmcnt(3)" ::: "memory");
      else       asm volatile("s_waitcnt vmcnt(2)" ::: "memory");
    } else {
      asm volatile("s_waitcnt vmcnt(0)" ::: "memory");
    }
    __builtin_amdgcn_s_barrier();

    const u16* L = &lds[cur][0];
    const f16x8 ah = ld8h(L + oAh + wm * 512 + lane * 8);
    const f16x8 al = ld8h(L + oAl + wm * 512 + lane * 8);
    #pragma unroll
    for (int gt = 0; gt < 3; ++gt) {
      const int g = gt * 2 + wn;
      const f16x8 bh = ld8h(L + oBh + g * 512 + lane * 8);
      const f16x8 bl = ld8h(L + oBl + g * 512 + lane * 8);
      acc[gt] = __builtin_amdgcn_mfma_f32_16x16x32_f16(ah, bh, acc[gt], 0, 0, 0);
      acc[gt] = __builtin_amdgcn_mfma_f32_16x16x32_f16(ah, bl, acc[gt], 0, 0, 0);
      acc[gt] = __builtin_amdgcn_mfma_f32_16x16x32_f16(al, bh, acc[gt], 0, 0, 0);
    }
    asm volatile("s_waitcnt lgkmcnt(0)" ::: "memory");
    __builtin_amdgcn_sched_barrier(0);
    __builtin_amdgcn_s_barrier();
    cur = (cur == 2) ? 0 : cur + 1;
  }

  const int c = bn + wn * 16 + lr;
  const float b_ir = bih[c], b_iz = bih[1024 + c], b_in = bih[2048 + c];
  const float b_hr = bhh[c], b_hz = bhh[1024 + c], b_hn = bhh[2048 + c];
  #pragma unroll
  for (int rr = 0; rr < 4; ++rr) {
    const int row = bm + wm * 16 + lg * 4 + rr;
    const size_t gr = (size_t)row * gi_rs;
    const float pr = gi[gr + c]        + b_ir + acc[0][rr] * INV2 + b_hr;
    const float pz = gi[gr + 1024 + c] + b_iz + acc[1][rr] * INV2 + b_hz;
    const float r = 1.f / (1.f + expf(-pr));
    const float z = 1.f / (1.f + expf(-pz));
    const float n = tanhf(gi[gr + 2048 + c] + b_in + r * (acc[2][rr] * INV2 + b_hn));
    const size_t o = (size_t)row * Hsz + c;
    const float h = (1.f - z) * n + z * hf_in[o];
    hf_out[o] = h;
    const float hs = h * WSCALE;
    const f16 hb = (f16)hs;
    const f16 lb = (f16)(hs - (float)hb);
    hho[o] = h2u(hb);
    hlo[o] = h2u(lb);
    const size_t o2 = ((size_t)row * Tsz + tstep) * Hsz + c;
    Hph[o2] = h2u(hb);
    Hpl[o2] = h2u(lb);
  }
}

// ============ PRE: P[b][t][l] = h[t] . G[b][l]  (3-pass fp16, per-batch) =======
__global__ __launch_bounds__(256) void k_pre(
    const u16* __restrict__ Hph, const u16* __restrict__ Hpl,
    const u16* __restrict__ Gh, const u16* __restrict__ Gl,
    float* __restrict__ P)
{
  const int b = blockIdx.x;
  const int w = threadIdx.x >> 6, lane = threadIdx.x & 63;
  const int wm = w >> 1, wn = w & 1;
  const int lr = lane & 15, lg = lane >> 4;

  const int t_ = wm * 16 + lr;
  const int l_ = wn * 16 + lr;
  const size_t abase = ((size_t)b * Tsz + t_) * Hsz + lg * 8;
  const size_t bbase = ((size_t)b * Tsz + l_) * Hsz + lg * 8;

  f32x4 acc = {};
  for (int k0 = 0; k0 < Hsz; k0 += 32) {
    const f16x8 ah = ld8h(Hph + abase + k0);
    const f16x8 al = ld8h(Hpl + abase + k0);
    const f16x8 bh = ld8h(Gh + bbase + k0);
    const f16x8 bl = ld8h(Gl + bbase + k0);
    acc = __builtin_amdgcn_mfma_f32_16x16x32_f16(ah, bh, acc, 0, 0, 0);
    acc = __builtin_amdgcn_mfma_f32_16x16x32_f16(ah, bl, acc, 0, 0, 0);
    acc = __builtin_amdgcn_mfma_f32_16x16x32_f16(al, bh, acc, 0, 0, 0);
  }

  #pragma unroll
  for (int rr = 0; rr < 4; ++rr) {
    const int tr = wm * 16 + lg * 4 + rr;
    P[(size_t)b * 1024 + tr * 32 + wn * 16 + lr] = acc[rr] * INV2;
  }
}

// ============ SM: masked softmax + argmax/flag chain, outputs ==================
__global__ __launch_bounds__(64) void k_sm(
    const float* __restrict__ P, const float* __restrict__ c0,
    const u32* __restrict__ valid, float* __restrict__ out)
{
  const int b = blockIdx.x;
  const int l = threadIdx.x;
  const bool act = (l < Lsz);
  const float c0l = act ? c0[b * Lsz + l] : 0.f;
  const u32 vmask = valid[b];
  u32 fl = 0;

  for (int t = 0; t < Tsz; ++t) {
    const float pre = act ? (P[(size_t)b * 1024 + t * 32 + l] + c0l) : 0.f;
    if (act) out[(size_t)b * (Tsz * Lsz) + t * Lsz + l] = pre;
    const u32 ex = fl | ~vmask;
    const bool ok = act && !((ex >> l) & 1u);
    const float v = ok ? pre : -3.4e38f;
    float best = v;
    #pragma unroll
    for (int off = 32; off >= 1; off >>= 1) best = fmaxf(best, __shfl_xor(best, off, 64));
    const unsigned long long msk = __ballot(v == best);
    const int am = __ffsll((long long)msk) - 1;
    const float e = ok ? expf(pre - best) : 0.f;
    float sum = e;
    #pragma unroll
    for (int off = 32; off >= 1; off >>= 1) sum += __shfl_xor(sum, off, 64);
    if (act)
      out[(size_t)Bsz * Tsz * Lsz + (size_t)b * (Tsz * Lsz) + t * Lsz + l] = e / sum;
    fl |= (1u << am);
  }
}

extern "C" void kernel_launch(void* const* d_in, const int* in_sizes, int n_in,
                              void* d_out, int out_size, void* d_ws, size_t ws_size,
                              hipStream_t stream) {
  const float* ih  = (const float*)d_in[0];
  const float* tg  = (const float*)d_in[1];
  const int*   pos = (const int*)d_in[2];
  const float* S   = (const float*)d_in[4];
  const float* wih = (const float*)d_in[5];
  const float* whh = (const float*)d_in[6];
  const float* bih = (const float*)d_in[7];
  const float* bhh = (const float*)d_in[8];
  const float* wlw = (const float*)d_in[9];
  const float* wlb = (const float*)d_in[10];
  float* out = (float*)d_out;

  const size_t NW3 = (size_t)3 * Hsz * Hsz;
  const size_t NW1 = (size_t)Hsz * Hsz;
  const size_t NH  = (size_t)Bsz * Hsz;
  const size_t NPL = ((size_t)Bsz * Tsz + 2) * Hsz;  // padded plane rows

  char* p = (char*)d_ws;
  u16* wihh = (u16*)p; p += NW3 * 2;
  u16* wihl = (u16*)p; p += NW3 * 2;
  u16* whhh = (u16*)p; p += NW3 * 2;
  u16* whhl = (u16*)p; p += NW3 * 2;
  u16* wlt0 = (u16*)p; p += NW1 * 2;
  u16* wlt1 = (u16*)p; p += NW1 * 2;
  float* ring = (float*)p; p += (size_t)8 * Bsz * 3072 * 4;   // 50.3 MB
  u16* Gh  = (u16*)p; p += NPL * 2;
  u16* Gl  = (u16*)p; p += NPL * 2;
  u16* Hph = (u16*)p; p += NPL * 2;
  u16* Hpl = (u16*)p; p += NPL * 2;
  float* P   = (float*)p; p += (size_t)Bsz * 1024 * 4;
  float* c0  = (float*)p; p += (size_t)Bsz * Lsz * 4;
  float* gi0 = (float*)p; p += 3072 * 4;
  float* hfb[2]; u16* hhb[2]; u16* hlb[2];
  hfb[0] = (float*)p; p += NH * 4;
  hfb[1] = (float*)p; p += NH * 4;
  hhb[0] = (u16*)p; p += NH * 2;
  hlb[0] = (u16*)p; p += NH * 2;
  hhb[1] = (u16*)p; p += NH * 2;
  hlb[1] = (u16*)p; p += NH * 2;
  u32* valid = (u32*)p; p += Bsz * 4;

  k_split<<<(int)(NW3 / 4 + 255) / 256, 256, 0, stream>>>(wih, wihh, wihl, (int)(NW3 / 4));
  k_split<<<(int)(NW3 / 4 + 255) / 256, 256, 0, stream>>>(whh, whhh, whhl, (int)(NW3 / 4));
  k_splitT2<<<dim3(32, 32), 256, 0, stream>>>(wlw, wlt0, wlt1);
  k_init<<<Bsz, 256, 0, stream>>>(ih, pos, wlb, hfb[0], hhb[0], hlb[0], c0, valid);
  k_gemv0<<<48, 256, 0, stream>>>(S, wih, gi0);
  // G planes = (ih @ WlT) * 32, fp16 hi/lo
  k_tgemm<0><<<dim3(8, 120), 256, 0, stream>>>(ih, wlt0, wlt1, nullptr, Gh, Gl, Hsz, 0);

  for (int t = 0; t < Tsz; ++t) {
    if (t == 1 || t == 9 || t == 17 || t == 25) {
      const int ns = (t == 25) ? 5 : 8;
      k_tgemm<1><<<dim3(24, ns * 4), 256, 0, stream>>>(tg, wihh, wihl, ring,
                                                       nullptr, nullptr, 3072, t);
    }
    const int ci = t & 1, ni = (t + 1) & 1;
    const float* gip = (t == 0) ? gi0 : (ring + (size_t)(t & 7) * Bsz * 3072);
    k_ghc<<<256, 512, 0, stream>>>(hhb[ci], hlb[ci], whhh, whhl,
                                   gip, (t == 0) ? 0 : 3072, bih, bhh,
                                   hfb[ci], hfb[ni], hhb[ni], hlb[ni],
                                   Hph, Hpl, t);
  }

  k_pre<<<Bsz, 256, 0, stream>>>(Hph, Hpl, Gh, Gl, P);
  k_sm<<<Bsz, 64, 0, stream>>>(P, c0, valid, out);
}

// Round 19
// 1472.497 us; speedup vs baseline: 1.4475x; 1.0009x over previous
//
#include <hip/hip_runtime.h>

#define Bsz 512
#define Lsz 30
#define Hsz 1024
#define Tsz 30

typedef _Float16 f16;
typedef f16 f16x8 __attribute__((ext_vector_type(8)));
typedef unsigned short u16x8 __attribute__((ext_vector_type(8)));
typedef float  f32x4  __attribute__((ext_vector_type(4)));
typedef unsigned int u32;
typedef unsigned short u16;

#define WSCALE 32.0f
#define INVWS  0.03125f
#define INV2   0.0009765625f   // 1/1024

__device__ __forceinline__ u16 h2u(f16 h) {
  union { f16 h; u16 u; } v; v.h = h; return v.u;
}
__device__ __forceinline__ f16x8 ld8h(const u16* p) {
  return *reinterpret_cast<const f16x8*>(p);
}
__device__ __forceinline__ void stage16(const u16* g, u16* l) {
  __builtin_amdgcn_global_load_lds(
      (const __attribute__((address_space(1))) u32*)g,
      (__attribute__((address_space(3))) u32*)l, 16, 0, 0);
}

// ------- split fp32 -> (hi, lo) fp16 planes, pre-scaled by WSCALE --------------
__global__ __launch_bounds__(256) void k_split(
    const float* __restrict__ src, u16* __restrict__ hi,
    u16* __restrict__ lo, int n4)
{
  const int i = blockIdx.x * 256 + threadIdx.x;
  if (i >= n4) return;
  const float4 v = ((const float4*)src)[i];
  const float f[4] = { v.x * WSCALE, v.y * WSCALE, v.z * WSCALE, v.w * WSCALE };
  u16 h[4], l[4];
  #pragma unroll
  for (int j = 0; j < 4; ++j) {
    const f16 hb = (f16)f[j];
    const f16 lb = (f16)(f[j] - (float)hb);
    h[j] = h2u(hb); l[j] = h2u(lb);
  }
  ((ushort4*)hi)[i] = make_ushort4(h[0], h[1], h[2], h[3]);
  ((ushort4*)lo)[i] = make_ushort4(l[0], l[1], l[2], l[3]);
}

// -------- transpose + scaled fp16 2-plane split: out[k][n] = in[n][k] (Wl) -----
__global__ __launch_bounds__(256) void k_splitT2(
    const float* __restrict__ src, u16* __restrict__ t0, u16* __restrict__ t1)
{
  __shared__ float t[32][33];
  const int tid = threadIdx.x;
  const int bi = blockIdx.x * 32, bj = blockIdx.y * 32;
  const int r = tid >> 3, c4 = (tid & 7) * 4;
  const float4 v = *(const float4*)(src + (size_t)(bi + r) * Hsz + bj + c4);
  t[r][c4] = v.x; t[r][c4 + 1] = v.y; t[r][c4 + 2] = v.z; t[r][c4 + 3] = v.w;
  __syncthreads();
  u16 h[4], l[4];
  #pragma unroll
  for (int i = 0; i < 4; ++i) {
    const float f = t[c4 + i][r] * WSCALE;
    const f16 hb = (f16)f;
    const f16 lb = (f16)(f - (float)hb);
    h[i] = h2u(hb); l[i] = h2u(lb);
  }
  const size_t o = (size_t)(bj + r) * Hsz + bi + c4;
  *(ushort4*)(t0 + o) = make_ushort4(h[0], h[1], h[2], h[3]);
  *(ushort4*)(t1 + o) = make_ushort4(l[0], l[1], l[2], l[3]);
}

// ------ init: h0 = mean_L(ih), scaled h fp16 splits, c0 = Wl_b . ih, valid -----
__global__ __launch_bounds__(256) void k_init(
    const float* __restrict__ ih, const int* __restrict__ pos,
    const float* __restrict__ wlb,
    float* __restrict__ hf, u16* __restrict__ hh,
    u16* __restrict__ hl, float* __restrict__ c0,
    u32* __restrict__ valid)
{
  __shared__ float red[4];
  const int b = blockIdx.x, tid = threadIdx.x;
  const int lane = tid & 63, wid = tid >> 6;
  const float4 wb = ((const float4*)wlb)[tid];
  float s0 = 0.f, s1 = 0.f, s2 = 0.f, s3 = 0.f;
  for (int l = 0; l < Lsz; ++l) {
    const float4 v = ((const float4*)(ih + ((size_t)b * Lsz + l) * Hsz))[tid];
    s0 += v.x; s1 += v.y; s2 += v.z; s3 += v.w;
    float part = v.x * wb.x + v.y * wb.y + v.z * wb.z + v.w * wb.w;
    #pragma unroll
    for (int off = 32; off >= 1; off >>= 1) part += __shfl_xor(part, off, 64);
    if (lane == 0) red[wid] = part;
    __syncthreads();
    if (tid == 0) c0[b * Lsz + l] = red[0] + red[1] + red[2] + red[3];
    __syncthreads();
  }
  const size_t o = (size_t)b * Hsz + tid * 4;
  const float m[4] = { s0 / 30.f, s1 / 30.f, s2 / 30.f, s3 / 30.f };
  *(float4*)(hf + o) = make_float4(m[0], m[1], m[2], m[3]);
  u16 h4[4], l4[4];
  #pragma unroll
  for (int j = 0; j < 4; ++j) {
    const float hs = m[j] * WSCALE;
    const f16 hb = (f16)hs;
    const f16 lb = (f16)(hs - (float)hb);
    h4[j] = h2u(hb); l4[j] = h2u(lb);
  }
  *(ushort4*)(hh + o) = make_ushort4(h4[0], h4[1], h4[2], h4[3]);
  *(ushort4*)(hl + o) = make_ushort4(l4[0], l4[1], l4[2], l4[3]);
  if (tid == 0) {
    int ss = 0;
    for (int l = 0; l < Lsz; ++l) ss += (pos[b * Lsz + l] != -1) ? 1 : 0;
    valid[b] = (ss >= 32) ? 0xFFFFFFFFu : ((1u << ss) - 1u);
  }
}

// ---------------- gi0 = S @ W_ih^T (fp32 GEMV, 3072 outputs) -------------------
__global__ __launch_bounds__(256) void k_gemv0(
    const float* __restrict__ S, const float* __restrict__ wih,
    float* __restrict__ gi0)
{
  const int n = blockIdx.x * 64 + (threadIdx.x >> 2);
  const int part = threadIdx.x & 3;
  const float4* s4 = (const float4*)S + part * 64;
  const float4* w4 = (const float4*)(wih + (size_t)n * Hsz) + part * 64;
  float s = 0.f;
  #pragma unroll 8
  for (int i = 0; i < 64; ++i) {
    const float4 a = s4[i], b = w4[i];
    s = fmaf(a.x, b.x, s); s = fmaf(a.y, b.y, s);
    s = fmaf(a.z, b.z, s); s = fmaf(a.w, b.w, s);
  }
  s += __shfl_xor(s, 1, 64);
  s += __shfl_xor(s, 2, 64);
  if (part == 0) gi0[n] = s;
}

// ============ 3-pass fp16 GEMM, counted-vmcnt pipeline =========================
// A double-buffered LDS (2x16KB) + reg ping-pong; B triple-buffered (3x16KB).
// Per step: LOAD_A(k+2), STAGE_B(k+2), vmcnt(12) [retires A(k+1)+B(k)],
// ds_write A(k+1), lgkm+bar, compute(k), lgkm+schedbar+bar. 80KB LDS, 2 blk/CU.
// MODE1 (GI): A-row remap into tgt, fp32 C into 8-slot ring, acc*INVWS.
// MODE0 (G):  plain A rows; acc (=32*G) split into fp16 planes Ch/Cl.
template<int MODE>
__global__ __launch_bounds__(256) void k_tgemm(
    const float* __restrict__ Afp,
    const u16* __restrict__ Bh, const u16* __restrict__ Bl,
    float* __restrict__ C, u16* __restrict__ Ch, u16* __restrict__ Cl,
    int ldc, int t0)
{
  __shared__ u16 ldsA[2][8192];
  __shared__ u16 ldsB[3][8192];

  const int tid = threadIdx.x;
  const int w = tid >> 6, lane = tid & 63;
  const int wm = w >> 1, wn = w & 1;
  const int lr = lane & 15, lg = lane >> 4;

  const int nwg = gridDim.x * gridDim.y;
  int lin = blockIdx.y * gridDim.x + blockIdx.x;
  lin = (lin & 7) * (nwg >> 3) + (lin >> 3);
  const int bm = (lin / gridDim.x) * 128, bn = (lin % gridDim.x) * 128;

  const int ar = tid & 127, kh = tid >> 7;
  long arow;
  if (MODE == 1) arow = (long)((bm + ar) & 511) * Tsz + (t0 - 1) + ((bm + ar) >> 9);
  else           arow = bm + ar;
  const float* aptr = Afp + arow * Hsz + kh * 16;
  const int awo0 = (ar >> 4) * 512 + ((ar & 15) + 32 * kh) * 8;

  const u16* gpB[4]; int bwo[4];
  #pragma unroll
  for (int i = 0; i < 4; ++i) {
    const int cid = (w << 2) | i;
    const u16* base; int g, off;
    if (cid < 8) { base = Bh; g = cid;     off = g * 512; }
    else         { base = Bl; g = cid - 8; off = 4096 + g * 512; }
    gpB[i] = base + (size_t)(bn + g * 16 + lr) * Hsz + lg * 8;
    bwo[i] = off;
  }

  float4 aA[4], aB[4];
  f32x4 acc[4][4] = {};

  #define TLOAD_A(AR) { _Pragma("unroll") for (int i = 0; i < 4; ++i) AR[i] = ((const float4*)aptr)[i]; aptr += 32; }
  #define TSTAGE_B(BB) { _Pragma("unroll") for (int i = 0; i < 4; ++i) { stage16(gpB[i], &ldsB[BB][bwo[i]]); gpB[i] += 32; } }
  #define TWRITE_A(AR, AB) { \
    u16x8 h0v, h1v, l0v, l1v; \
    _Pragma("unroll") for (int i = 0; i < 4; ++i) { \
      const float f[4] = { AR[i].x, AR[i].y, AR[i].z, AR[i].w }; \
      _Pragma("unroll") for (int c = 0; c < 4; ++c) { \
        const int j = 4 * i + c; \
        const f16 hb = (f16)f[c]; \
        const f16 lb = (f16)(f[c] - (float)hb); \
        if (j < 8) { h0v[j] = h2u(hb); l0v[j] = h2u(lb); } \
        else       { h1v[j - 8] = h2u(hb); l1v[j - 8] = h2u(lb); } \
      } \
    } \
    *(u16x8*)&ldsA[AB][awo0]              = h0v; \
    *(u16x8*)&ldsA[AB][awo0 + 128]        = h1v; \
    *(u16x8*)&ldsA[AB][4096 + awo0]       = l0v; \
    *(u16x8*)&ldsA[AB][4096 + awo0 + 128] = l1v; }
  #define TCOMPUTE(AB, BB) { \
    f16x8 a_h[4], a_l[4], b_h[4], b_l[4]; \
    _Pragma("unroll") for (int m = 0; m < 4; ++m) { \
      const int g = wm * 4 + m; \
      a_h[m] = ld8h(&ldsA[AB][g * 512 + lane * 8]); \
      a_l[m] = ld8h(&ldsA[AB][4096 + g * 512 + lane * 8]); \
    } \
    _Pragma("unroll") for (int n = 0; n < 4; ++n) { \
      const int g = wn * 4 + n; \
      b_h[n] = ld8h(&ldsB[BB][g * 512 + lane * 8]); \
      b_l[n] = ld8h(&ldsB[BB][4096 + g * 512 + lane * 8]); \
    } \
    _Pragma("unroll") for (int m = 0; m < 4; ++m) \
      _Pragma("unroll") for (int n = 0; n < 4; ++n) { \
        acc[m][n] = __builtin_amdgcn_mfma_f32_16x16x32_f16(a_h[m], b_h[n], acc[m][n], 0, 0, 0); \
        acc[m][n] = __builtin_amdgcn_mfma_f32_16x16x32_f16(a_h[m], b_l[n], acc[m][n], 0, 0, 0); \
        acc[m][n] = __builtin_amdgcn_mfma_f32_16x16x32_f16(a_l[m], b_h[n], acc[m][n], 0, 0, 0); \
      } }
  #define TSTEP(AN, AC, WAB, CAB, SBB, CBB) { \
    TLOAD_A(AN); \
    TSTAGE_B(SBB); \
    asm volatile("s_waitcnt vmcnt(12)" ::: "memory"); \
    TWRITE_A(AC, WAB); \
    asm volatile("s_waitcnt lgkmcnt(0)" ::: "memory"); \
    __builtin_amdgcn_s_barrier(); \
    TCOMPUTE(CAB, CBB); \
    asm volatile("s_waitcnt lgkmcnt(0)" ::: "memory"); \
    __builtin_amdgcn_sched_barrier(0); \
    __builtin_amdgcn_s_barrier(); }

  // prologue: A(0),A(1) loads; B(0),B(1) stages; write A(0)
  TLOAD_A(aA);
  TLOAD_A(aB);
  TSTAGE_B(0);
  TSTAGE_B(1);
  asm volatile("s_waitcnt vmcnt(12)" ::: "memory");   // A(0) ready
  TWRITE_A(aA, 0);

  // steady state: ks = 6*kb + j, j = 0..5 (all indices static per position)
  for (int kb = 0; kb < 5; ++kb) {
    TSTEP(aA, aB, 1, 0, 2, 0);   // ks%6==0
    TSTEP(aB, aA, 0, 1, 0, 1);   // ks%6==1
    TSTEP(aA, aB, 1, 0, 1, 2);   // ks%6==2
    TSTEP(aB, aA, 0, 1, 2, 0);   // ks%6==3
    TSTEP(aA, aB, 1, 0, 0, 1);   // ks%6==4
    TSTEP(aB, aA, 0, 1, 1, 2);   // ks%6==5
  }

  // tail ks=30: compute abuf0/bbuf0; write A(31) (in aB)
  asm volatile("s_waitcnt vmcnt(4)" ::: "memory");    // A(31) ready, B(30) landed
  TWRITE_A(aB, 1);
  asm volatile("s_waitcnt lgkmcnt(0)" ::: "memory");
  __builtin_amdgcn_s_barrier();
  TCOMPUTE(0, 0);
  asm volatile("s_waitcnt lgkmcnt(0)" ::: "memory");
  __builtin_amdgcn_sched_barrier(0);
  __builtin_amdgcn_s_barrier();
  // tail ks=31: compute abuf1/bbuf1
  asm volatile("s_waitcnt vmcnt(0)" ::: "memory");    // B(31) landed
  __builtin_amdgcn_s_barrier();
  TCOMPUTE(1, 1);

  #pragma unroll
  for (int n = 0; n < 4; ++n) {
    const int col = bn + wn * 64 + n * 16 + lr;
    #pragma unroll
    for (int m = 0; m < 4; ++m) {
      #pragma unroll
      for (int rr = 0; rr < 4; ++rr) {
        const int row = bm + wm * 64 + m * 16 + lg * 4 + rr;
        if (MODE == 1) {
          const int slot = (t0 + (row >> 9)) & 7;
          C[((size_t)slot * Bsz + (row & 511)) * 3072 + col] = acc[m][n][rr] * INVWS;
        } else {
          const float v = acc[m][n][rr];                // = 32 * G
          const f16 hb = (f16)v;
          const f16 lb = (f16)(v - (float)hb);
          Ch[(size_t)row * ldc + col] = h2u(hb);
          Cl[(size_t)row * ldc + col] = h2u(lb);
        }
      }
    }
  }
  #undef TLOAD_A
  #undef TSTAGE_B
  #undef TWRITE_A
  #undef TCOMPUTE
  #undef TSTEP
}

// ============ ghc: gh-GEMM (3 gates) + GRU combine, 8 waves, 64x32 =============
// COUNTED-VMCNT pipeline: 3 LDS buffers, 2-deep prefetch, raw s_barrier.
__global__ __launch_bounds__(512) void k_ghc(
    const u16* __restrict__ Hh, const u16* __restrict__ Hl,
    const u16* __restrict__ Wh, const u16* __restrict__ Wl,
    const float* __restrict__ gi, int gi_rs,
    const float* __restrict__ bih, const float* __restrict__ bhh,
    const float* __restrict__ hf_in, float* __restrict__ hf_out,
    u16* __restrict__ hho, u16* __restrict__ hlo,
    u16* __restrict__ Hph, u16* __restrict__ Hpl, int tstep)
{
  constexpr int oAh = 0, oAl = 2048, oBh = 4096, oBl = 7168;
  __shared__ u16 lds[3][10240];   // 60 KB

  const int bn = (blockIdx.x & 31) * 32, bm = (blockIdx.x >> 5) * 64;
  const int tid = threadIdx.x;
  const int w = tid >> 6, lane = tid & 63;
  const int wm = w >> 1, wn = w & 1;
  const int lr = lane & 15, lg = lane >> 4;

  const u16* gp[3]; int ldso[3];
  const int nch = (w < 4) ? 3 : 2;
  #pragma unroll
  for (int i = 0; i < 3; ++i) {
    const int cid = w + 8 * i;
    if (cid >= 20) break;
    const u16* base; long row; int off;
    if (cid < 4)       { const int g = cid;      row = bm + g * 16 + lr;                         base = Hh; off = oAh + g * 512; }
    else if (cid < 8)  { const int g = cid - 4;  row = bm + g * 16 + lr;                         base = Hl; off = oAl + g * 512; }
    else if (cid < 14) { const int g = cid - 8;  row = (g >> 1) * 1024 + bn + (g & 1) * 16 + lr; base = Wh; off = oBh + g * 512; }
    else               { const int g = cid - 14; row = (g >> 1) * 1024 + bn + (g & 1) * 16 + lr; base = Wl; off = oBl + g * 512; }
    gp[i] = base + row * Hsz + lg * 8;
    ldso[i] = off;
  }

  f32x4 acc[3] = {};

  for (int i = 0; i < nch; ++i) { stage16(gp[i], &lds[0][ldso[i]]); gp[i] += 32; }
  for (int i = 0; i < nch; ++i) { stage16(gp[i], &lds[1][ldso[i]]); gp[i] += 32; }

  int cur = 0;
  for (int ks = 0; ks < 32; ++ks) {
    if (ks < 30) {
      const int nxt2 = (cur >= 1) ? cur - 1 : cur + 2;
      for (int i = 0; i < nch; ++i) { stage16(gp[i], &lds[nxt2][ldso[i]]); gp[i] += 32; }
      if (w < 4) asm volatile("s_waitcnt vmcnt(6)" ::: "memory");
      else       asm volatile("s_waitcnt vmcnt(4)" ::: "memory");
    } else if (ks == 30) {
      if (w < 4) asm volatile("s_waitcnt vmcnt(3)" ::: "memory");
      else       asm volatile("s_waitcnt vmcnt(2)" ::: "memory");
    } else {
      asm volatile("s_waitcnt vmcnt(0)" ::: "memory");
    }
    __builtin_amdgcn_s_barrier();

    const u16* L = &lds[cur][0];
    const f16x8 ah = ld8h(L + oAh + wm * 512 + lane * 8);
    const f16x8 al = ld8h(L + oAl + wm * 512 + lane * 8);
    #pragma unroll
    for (int gt = 0; gt < 3; ++gt) {
      const int g = gt * 2 + wn;
      const f16x8 bh = ld8h(L + oBh + g * 512 + lane * 8);
      const f16x8 bl = ld8h(L + oBl + g * 512 + lane * 8);
      acc[gt] = __builtin_amdgcn_mfma_f32_16x16x32_f16(ah, bh, acc[gt], 0, 0, 0);
      acc[gt] = __builtin_amdgcn_mfma_f32_16x16x32_f16(ah, bl, acc[gt], 0, 0, 0);
      acc[gt] = __builtin_amdgcn_mfma_f32_16x16x32_f16(al, bh, acc[gt], 0, 0, 0);
    }
    asm volatile("s_waitcnt lgkmcnt(0)" ::: "memory");
    __builtin_amdgcn_sched_barrier(0);
    __builtin_amdgcn_s_barrier();
    cur = (cur == 2) ? 0 : cur + 1;
  }

  const int c = bn + wn * 16 + lr;
  const float b_ir = bih[c], b_iz = bih[1024 + c], b_in = bih[2048 + c];
  const float b_hr = bhh[c], b_hz = bhh[1024 + c], b_hn = bhh[2048 + c];
  #pragma unroll
  for (int rr = 0; rr < 4; ++rr) {
    const int row = bm + wm * 16 + lg * 4 + rr;
    const size_t gr = (size_t)row * gi_rs;
    const float pr = gi[gr + c]        + b_ir + acc[0][rr] * INV2 + b_hr;
    const float pz = gi[gr + 1024 + c] + b_iz + acc[1][rr] * INV2 + b_hz;
    const float r = 1.f / (1.f + expf(-pr));
    const float z = 1.f / (1.f + expf(-pz));
    const float n = tanhf(gi[gr + 2048 + c] + b_in + r * (acc[2][rr] * INV2 + b_hn));
    const size_t o = (size_t)row * Hsz + c;
    const float h = (1.f - z) * n + z * hf_in[o];
    hf_out[o] = h;
    const float hs = h * WSCALE;
    const f16 hb = (f16)hs;
    const f16 lb = (f16)(hs - (float)hb);
    hho[o] = h2u(hb);
    hlo[o] = h2u(lb);
    const size_t o2 = ((size_t)row * Tsz + tstep) * Hsz + c;
    Hph[o2] = h2u(hb);
    Hpl[o2] = h2u(lb);
  }
}

// ============ PRE: P[b][t][l] = h[t] . G[b][l]  (3-pass fp16, per-batch) =======
__global__ __launch_bounds__(256) void k_pre(
    const u16* __restrict__ Hph, const u16* __restrict__ Hpl,
    const u16* __restrict__ Gh, const u16* __restrict__ Gl,
    float* __restrict__ P)
{
  const int b = blockIdx.x;
  const int w = threadIdx.x >> 6, lane = threadIdx.x & 63;
  const int wm = w >> 1, wn = w & 1;
  const int lr = lane & 15, lg = lane >> 4;

  const int t_ = wm * 16 + lr;
  const int l_ = wn * 16 + lr;
  const size_t abase = ((size_t)b * Tsz + t_) * Hsz + lg * 8;
  const size_t bbase = ((size_t)b * Tsz + l_) * Hsz + lg * 8;

  f32x4 acc = {};
  for (int k0 = 0; k0 < Hsz; k0 += 32) {
    const f16x8 ah = ld8h(Hph + abase + k0);
    const f16x8 al = ld8h(Hpl + abase + k0);
    const f16x8 bh = ld8h(Gh + bbase + k0);
    const f16x8 bl = ld8h(Gl + bbase + k0);
    acc = __builtin_amdgcn_mfma_f32_16x16x32_f16(ah, bh, acc, 0, 0, 0);
    acc = __builtin_amdgcn_mfma_f32_16x16x32_f16(ah, bl, acc, 0, 0, 0);
    acc = __builtin_amdgcn_mfma_f32_16x16x32_f16(al, bh, acc, 0, 0, 0);
  }

  #pragma unroll
  for (int rr = 0; rr < 4; ++rr) {
    const int tr = wm * 16 + lg * 4 + rr;
    P[(size_t)b * 1024 + tr * 32 + wn * 16 + lr] = acc[rr] * INV2;
  }
}

// ============ SM: masked softmax + argmax/flag chain, outputs ==================
__global__ __launch_bounds__(64) void k_sm(
    const float* __restrict__ P, const float* __restrict__ c0,
    const u32* __restrict__ valid, float* __restrict__ out)
{
  const int b = blockIdx.x;
  const int l = threadIdx.x;
  const bool act = (l < Lsz);
  const float c0l = act ? c0[b * Lsz + l] : 0.f;
  const u32 vmask = valid[b];
  u32 fl = 0;

  for (int t = 0; t < Tsz; ++t) {
    const float pre = act ? (P[(size_t)b * 1024 + t * 32 + l] + c0l) : 0.f;
    if (act) out[(size_t)b * (Tsz * Lsz) + t * Lsz + l] = pre;
    const u32 ex = fl | ~vmask;
    const bool ok = act && !((ex >> l) & 1u);
    const float v = ok ? pre : -3.4e38f;
    float best = v;
    #pragma unroll
    for (int off = 32; off >= 1; off >>= 1) best = fmaxf(best, __shfl_xor(best, off, 64));
    const unsigned long long msk = __ballot(v == best);
    const int am = __ffsll((long long)msk) - 1;
    const float e = ok ? expf(pre - best) : 0.f;
    float sum = e;
    #pragma unroll
    for (int off = 32; off >= 1; off >>= 1) sum += __shfl_xor(sum, off, 64);
    if (act)
      out[(size_t)Bsz * Tsz * Lsz + (size_t)b * (Tsz * Lsz) + t * Lsz + l] = e / sum;
    fl |= (1u << am);
  }
}

extern "C" void kernel_launch(void* const* d_in, const int* in_sizes, int n_in,
                              void* d_out, int out_size, void* d_ws, size_t ws_size,
                              hipStream_t stream) {
  const float* ih  = (const float*)d_in[0];
  const float* tg  = (const float*)d_in[1];
  const int*   pos = (const int*)d_in[2];
  const float* S   = (const float*)d_in[4];
  const float* wih = (const float*)d_in[5];
  const float* whh = (const float*)d_in[6];
  const float* bih = (const float*)d_in[7];
  const float* bhh = (const float*)d_in[8];
  const float* wlw = (const float*)d_in[9];
  const float* wlb = (const float*)d_in[10];
  float* out = (float*)d_out;

  const size_t NW3 = (size_t)3 * Hsz * Hsz;
  const size_t NW1 = (size_t)Hsz * Hsz;
  const size_t NH  = (size_t)Bsz * Hsz;
  const size_t NPL = ((size_t)Bsz * Tsz + 2) * Hsz;  // padded plane rows

  char* p = (char*)d_ws;
  u16* wihh = (u16*)p; p += NW3 * 2;
  u16* wihl = (u16*)p; p += NW3 * 2;
  u16* whhh = (u16*)p; p += NW3 * 2;
  u16* whhl = (u16*)p; p += NW3 * 2;
  u16* wlt0 = (u16*)p; p += NW1 * 2;
  u16* wlt1 = (u16*)p; p += NW1 * 2;
  float* ring = (float*)p; p += (size_t)8 * Bsz * 3072 * 4;   // 50.3 MB
  u16* Gh  = (u16*)p; p += NPL * 2;
  u16* Gl  = (u16*)p; p += NPL * 2;
  u16* Hph = (u16*)p; p += NPL * 2;
  u16* Hpl = (u16*)p; p += NPL * 2;
  float* P   = (float*)p; p += (size_t)Bsz * 1024 * 4;
  float* c0  = (float*)p; p += (size_t)Bsz * Lsz * 4;
  float* gi0 = (float*)p; p += 3072 * 4;
  float* hfb[2]; u16* hhb[2]; u16* hlb[2];
  hfb[0] = (float*)p; p += NH * 4;
  hfb[1] = (float*)p; p += NH * 4;
  hhb[0] = (u16*)p; p += NH * 2;
  hlb[0] = (u16*)p; p += NH * 2;
  hhb[1] = (u16*)p; p += NH * 2;
  hlb[1] = (u16*)p; p += NH * 2;
  u32* valid = (u32*)p; p += Bsz * 4;

  k_split<<<(int)(NW3 / 4 + 255) / 256, 256, 0, stream>>>(wih, wihh, wihl, (int)(NW3 / 4));
  k_split<<<(int)(NW3 / 4 + 255) / 256, 256, 0, stream>>>(whh, whhh, whhl, (int)(NW3 / 4));
  k_splitT2<<<dim3(32, 32), 256, 0, stream>>>(wlw, wlt0, wlt1);
  k_init<<<Bsz, 256, 0, stream>>>(ih, pos, wlb, hfb[0], hhb[0], hlb[0], c0, valid);
  k_gemv0<<<48, 256, 0, stream>>>(S, wih, gi0);
  // G planes = (ih @ WlT) * 32, fp16 hi/lo
  k_tgemm<0><<<dim3(8, 120), 256, 0, stream>>>(ih, wlt0, wlt1, nullptr, Gh, Gl, Hsz, 0);

  for (int t = 0; t < Tsz; ++t) {
    if (t == 1 || t == 9 || t == 17 || t == 25) {
      const int ns = (t == 25) ? 5 : 8;
      k_tgemm<1><<<dim3(24, ns * 4), 256, 0, stream>>>(tg, wihh, wihl, ring,
                                                       nullptr, nullptr, 3072, t);
    }
    const int ci = t & 1, ni = (t + 1) & 1;
    const float* gip = (t == 0) ? gi0 : (ring + (size_t)(t & 7) * Bsz * 3072);
    k_ghc<<<256, 512, 0, stream>>>(hhb[ci], hlb[ci], whhh, whhl,
                                   gip, (t == 0) ? 0 : 3072, bih, bhh,
                                   hfb[ci], hfb[ni], hhb[ni], hlb[ni],
                                   Hph, Hpl, t);
  }

  k_pre<<<Bsz, 256, 0, stream>>>(Hph, Hpl, Gh, Gl, P);
  k_sm<<<Bsz, 64, 0, stream>>>(P, c0, valid, out);
}